// Round 10
// baseline (567.062 us; speedup 1.0000x reference)
//
#include <hip/hip_runtime.h>
#include <hip/hip_cooperative_groups.h>
#include <math.h>

// Problem constants (UnifiedMambaBlock, B=1)
#define L      4096
#define DM     768
#define DI     1536
#define DS     16
#define DR     48
#define NCOMB  80     // 48 dt_rank + 16 B + 16 C
#define CH     32     // scan chunk length
#define NC     128    // number of chunks (L / CH)
#define G2_S   16     // GEMM2 K-splits
#define G2_KC  96     // 1536 / 16
#define XZROW  6144   // xz row stride in u16 (3072 floats)

typedef unsigned short u16;
typedef unsigned int   u32;
typedef __attribute__((ext_vector_type(8))) short bf16x8;   // 8 bf16 = 4 VGPRs
typedef __attribute__((ext_vector_type(4))) float f32x4;

__device__ __forceinline__ float silu_f(float v) { return v / (1.f + __expf(-v)); }

__device__ __forceinline__ u16 f2bf(float f) {              // RNE f32 -> bf16
    u32 u = __float_as_uint(f);
    return (u16)((u + 0x7fffu + ((u >> 16) & 1u)) >> 16);
}
__device__ __forceinline__ float bf2f(u16 h) {
    return __uint_as_float(((u32)h) << 16);
}

__device__ __forceinline__ float softplus_f(float s) {
    return (s > 20.f) ? s : log1pf(expf(s));
}

__device__ __forceinline__ void gl_lds16(const u16* g, u16* l) {
    __builtin_amdgcn_global_load_lds(
        (const __attribute__((address_space(1))) void*)g,
        (__attribute__((address_space(3))) void*)l, 16, 0, 0);
}

// ---------------------------------------------------------------------------
// bf16 MFMA GEMM (m97 structure): C[M,N] fp32 = A[M,K] @ W[N,K]^T, bf16 in.
// 128x128 tile, BK=32, 256 threads (4 waves, 2x2 of 64x64), double-buffer LDS.
// ---------------------------------------------------------------------------
__global__ __launch_bounds__(256)
void gemm_bf16_bt(const u16* __restrict__ A, const u16* __restrict__ W,
                  float* __restrict__ C, int M, int N, int K)
{
    __shared__ u16 As[2][128 * 32];
    __shared__ u16 Bs[2][128 * 32];

    const int tid  = threadIdx.x;
    const int lane = tid & 63;
    const int wave = tid >> 6;
    const int wr   = (wave >> 1) * 64;
    const int wc   = (wave & 1) * 64;
    const int m0   = blockIdx.y * 128;
    const int n0   = blockIdx.x * 128;

    const int r0 = tid >> 2;
    const int k0 = (tid & 3) * 8;

    const int frow = lane & 15;
    const int fk   = (lane >> 4) * 8;

    f32x4 acc[4][4];
    #pragma unroll
    for (int i = 0; i < 4; ++i)
        #pragma unroll
        for (int j = 0; j < 4; ++j)
            acc[i][j] = (f32x4){0.f, 0.f, 0.f, 0.f};

    const int NT = K >> 5;

#define STAGE(buf, kk) {                                                       \
        const u16* ga = A + (size_t)(m0 + r0) * K + (kk) + k0;                 \
        const u16* gw = W + (size_t)(n0 + r0) * K + (kk) + k0;                 \
        gl_lds16(ga,                   &As[buf][tid * 8]);                     \
        gl_lds16(ga + (size_t)64 * K,  &As[buf][2048 + tid * 8]);              \
        gl_lds16(gw,                   &Bs[buf][tid * 8]);                     \
        gl_lds16(gw + (size_t)64 * K,  &Bs[buf][2048 + tid * 8]); }

    STAGE(0, 0);
    __syncthreads();

    for (int t = 0; t < NT; ++t) {
        const int b = t & 1;
        if (t + 1 < NT) STAGE(b ^ 1, (t + 1) << 5);

        bf16x8 af[4], bw[4];
        #pragma unroll
        for (int m = 0; m < 4; ++m)
            af[m] = *(const bf16x8*)&As[b][(wr + m * 16 + frow) * 32 + fk];
        #pragma unroll
        for (int n = 0; n < 4; ++n)
            bw[n] = *(const bf16x8*)&Bs[b][(wc + n * 16 + frow) * 32 + fk];

        #pragma unroll
        for (int m = 0; m < 4; ++m)
            #pragma unroll
            for (int n = 0; n < 4; ++n)
                acc[m][n] = __builtin_amdgcn_mfma_f32_16x16x32_bf16(
                    af[m], bw[n], acc[m][n], 0, 0, 0);

        __syncthreads();
    }
#undef STAGE

    const int crow = (lane >> 4) * 4;
    const int ccol = lane & 15;
    #pragma unroll
    for (int m = 0; m < 4; ++m)
        #pragma unroll
        for (int n = 0; n < 4; ++n)
            #pragma unroll
            for (int r = 0; r < 4; ++r)
                C[(size_t)(m0 + wr + m * 16 + crow + r) * N
                  + n0 + wc + n * 16 + ccol] = acc[m][n][r];
}

// ---------------------------------------------------------------------------
// bf16 MFMA GEMM with strided rows (lda/ldw in u16 elems), 128(M)x64(N) tile.
// ---------------------------------------------------------------------------
__global__ __launch_bounds__(256)
void gemm_bf16_bt_n64(const u16* __restrict__ A, int lda,
                      const u16* __restrict__ W, int ldw,
                      float* __restrict__ C, int M, int N, int K)
{
    __shared__ u16 As[2][128 * 32];
    __shared__ u16 Bs[2][64 * 32];

    const int tid  = threadIdx.x;
    const int lane = tid & 63;
    const int wave = tid >> 6;
    const int wr   = (wave >> 1) * 64;
    const int wc   = (wave & 1) * 32;
    const int m0   = blockIdx.y * 128;
    const int n0   = blockIdx.x * 64;

    const int r0 = tid >> 2;
    const int k0 = (tid & 3) * 8;

    const int frow = lane & 15;
    const int fk   = (lane >> 4) * 8;

    f32x4 acc[4][2];
    #pragma unroll
    for (int i = 0; i < 4; ++i)
        #pragma unroll
        for (int j = 0; j < 2; ++j)
            acc[i][j] = (f32x4){0.f, 0.f, 0.f, 0.f};

    const int NT = K >> 5;

#define STG(buf, kk) {                                                         \
        const u16* ga = A + (size_t)(m0 + r0) * lda + (kk) + k0;               \
        gl_lds16(ga,                     &As[buf][tid * 8]);                   \
        gl_lds16(ga + (size_t)64 * lda,  &As[buf][2048 + tid * 8]);            \
        gl_lds16(W + (size_t)(n0 + r0) * ldw + (kk) + k0, &Bs[buf][tid * 8]); }

    STG(0, 0);
    __syncthreads();

    for (int t = 0; t < NT; ++t) {
        const int b = t & 1;
        if (t + 1 < NT) STG(b ^ 1, (t + 1) << 5);

        bf16x8 af[4], bw[2];
        #pragma unroll
        for (int m = 0; m < 4; ++m)
            af[m] = *(const bf16x8*)&As[b][(wr + m * 16 + frow) * 32 + fk];
        #pragma unroll
        for (int n = 0; n < 2; ++n)
            bw[n] = *(const bf16x8*)&Bs[b][(wc + n * 16 + frow) * 32 + fk];

        #pragma unroll
        for (int m = 0; m < 4; ++m)
            #pragma unroll
            for (int n = 0; n < 2; ++n)
                acc[m][n] = __builtin_amdgcn_mfma_f32_16x16x32_bf16(
                    af[m], bw[n], acc[m][n], 0, 0, 0);

        __syncthreads();
    }
#undef STG

    const int crow = (lane >> 4) * 4;
    const int ccol = lane & 15;
    #pragma unroll
    for (int m = 0; m < 4; ++m)
        #pragma unroll
        for (int n = 0; n < 2; ++n)
            #pragma unroll
            for (int r = 0; r < 4; ++r)
                C[(size_t)(m0 + wr + m * 16 + crow + r) * N
                  + n0 + wc + n * 16 + ccol] = acc[m][n][r];
}

// ---------------------------------------------------------------------------
// Early pack: u -> ubf, Wip -> Wipb (bf16), [xdt;xb;xc]^T -> Wt (fp32),
// Aneg = -exp(A_log)
// ---------------------------------------------------------------------------
#define NU4  (L * DM / 4)            // 786432
#define NW4  (2 * DI * DM / 4)       // 589824
#define NWT  (DI * NCOMB)            // 122880
#define NA   (DI * DS)               // 24576
__global__ __launch_bounds__(256)
void pack_early_k(const float* __restrict__ u, const float* __restrict__ Wip,
                  const float* __restrict__ xdt, const float* __restrict__ xb,
                  const float* __restrict__ xc, const float* __restrict__ alog,
                  u16* __restrict__ ubf, u16* __restrict__ Wipb,
                  float* __restrict__ Wt, float* __restrict__ Aneg)
{
    int i = blockIdx.x * 256 + threadIdx.x;
    if (i < NU4) {
        const float4 v = ((const float4*)u)[i];
        ushort4 o; o.x = f2bf(v.x); o.y = f2bf(v.y); o.z = f2bf(v.z); o.w = f2bf(v.w);
        ((ushort4*)ubf)[i] = o;
        return;
    }
    i -= NU4;
    if (i < NW4) {
        const float4 v = ((const float4*)Wip)[i];
        ushort4 o; o.x = f2bf(v.x); o.y = f2bf(v.y); o.z = f2bf(v.z); o.w = f2bf(v.w);
        ((ushort4*)Wipb)[i] = o;
        return;
    }
    i -= NW4;
    if (i < NWT) {
        const int k = i / NCOMB, n = i - k * NCOMB;
        float v;
        if (n < 48)      v = xdt[n * DI + k];
        else if (n < 64) v = xb[(n - 48) * DI + k];
        else             v = xc[(n - 64) * DI + k];
        Wt[i] = v;
        return;
    }
    i -= NWT;
    if (i < NA)
        Aneg[i] = -expf(alog[i]);
}

// ---------------------------------------------------------------------------
// Wop -> bf16, scattered into dead x-half of xz rows (row r, u16 cols 1536+c)
// ---------------------------------------------------------------------------
#define NO4  (DM * DI / 4)           // 294912
__global__ __launch_bounds__(256)
void pack_wop_k(const float* __restrict__ Wop, u16* __restrict__ xzu)
{
    int i = blockIdx.x * 256 + threadIdx.x;
    if (i >= NO4) return;
    const float4 v = ((const float4*)Wop)[i];
    ushort4 o; o.x = f2bf(v.x); o.y = f2bf(v.y); o.z = f2bf(v.z); o.w = f2bf(v.w);
    const int e = i * 4;
    const int r = e / DI, c = e - r * DI;
    *(ushort4*)(xzu + (size_t)r * XZROW + 1536 + c) = o;
}

// ---------------------------------------------------------------------------
// Vectorized causal depthwise conv (width 4) + bias + SiLU: 4 channels/thread
// ---------------------------------------------------------------------------
__global__ __launch_bounds__(256)
void conv_silu_v4(const float* __restrict__ xz, const float* __restrict__ cw,
                  const float* __restrict__ cb, float* __restrict__ xcv)
{
    int idx = blockIdx.x * 256 + threadIdx.x;
    if (idx >= L * (DI / 4)) return;
    const int t = idx / (DI / 4);
    const int q = idx - t * (DI / 4);
    const int d = q * 4;

    const float4 w0 = ((const float4*)cw)[d + 0];
    const float4 w1 = ((const float4*)cw)[d + 1];
    const float4 w2 = ((const float4*)cw)[d + 2];
    const float4 w3 = ((const float4*)cw)[d + 3];
    float4 acc = ((const float4*)cb)[q];

    const float* base = xz + d;
    #pragma unroll
    for (int j = 0; j < 4; ++j) {
        const int tt = t - 3 + j;
        if (tt >= 0) {
            const float4 x = *(const float4*)(base + (size_t)tt * (2 * DI));
            acc.x = fmaf(((const float*)&w0)[j], x.x, acc.x);
            acc.y = fmaf(((const float*)&w1)[j], x.y, acc.y);
            acc.z = fmaf(((const float*)&w2)[j], x.z, acc.z);
            acc.w = fmaf(((const float*)&w3)[j], x.w, acc.w);
        }
    }
    float4 o;
    o.x = silu_f(acc.x); o.y = silu_f(acc.y);
    o.z = silu_f(acc.z); o.w = silu_f(acc.w);
    ((float4*)xcv)[idx] = o;
}

// ---------------------------------------------------------------------------
// GEMM2 split-K: part[s][L][80] = xcv[L][DI-slice] @ Wt[DI-slice][80]
// ---------------------------------------------------------------------------
__global__ __launch_bounds__(256)
void gemm2_splitk(const float* __restrict__ A, const float* __restrict__ Wt,
                  float* __restrict__ part)
{
    __shared__ float As[G2_KC][65];     // +1 pad
    __shared__ float Ws[G2_KC][80];

    const int tid  = threadIdx.x;
    const int m0   = blockIdx.x * 64;
    const int koff = blockIdx.y * G2_KC;

    {
        const int r = tid >> 2, cg = tid & 3;
        #pragma unroll
        for (int j = 0; j < 6; ++j) {
            const int kk = (j * 4 + cg) * 4;
            const float4 v = *(const float4*)(A + (size_t)(m0 + r) * DI + koff + kk);
            As[kk + 0][r] = v.x; As[kk + 1][r] = v.y;
            As[kk + 2][r] = v.z; As[kk + 3][r] = v.w;
        }
    }
    for (int i = tid; i < G2_KC * 80; i += 256)
        (&Ws[0][0])[i] = Wt[(size_t)koff * 80 + i];
    __syncthreads();

    const int g  = tid >> 6;
    const int r  = tid & 63;
    const int c0 = g * 20;

    float acc[20];
    #pragma unroll
    for (int j = 0; j < 20; ++j) acc[j] = 0.f;

    #pragma unroll 2
    for (int k = 0; k < G2_KC; ++k) {
        const float a = As[k][r];
        #pragma unroll
        for (int q = 0; q < 5; ++q) {
            const float4 w = *(const float4*)&Ws[k][c0 + q * 4];
            acc[q * 4 + 0] = fmaf(a, w.x, acc[q * 4 + 0]);
            acc[q * 4 + 1] = fmaf(a, w.y, acc[q * 4 + 1]);
            acc[q * 4 + 2] = fmaf(a, w.z, acc[q * 4 + 2]);
            acc[q * 4 + 3] = fmaf(a, w.w, acc[q * 4 + 3]);
        }
    }

    float* p = part + (size_t)blockIdx.y * (L * NCOMB)
                    + (size_t)(m0 + r) * NCOMB + c0;
    #pragma unroll
    for (int q = 0; q < 5; ++q)
        ((float4*)p)[q] = make_float4(acc[q * 4], acc[q * 4 + 1],
                                      acc[q * 4 + 2], acc[q * 4 + 3]);
}

__global__ __launch_bounds__(256)
void gemm2_reduce(const float* __restrict__ part, float* __restrict__ dtbc)
{
    int i = blockIdx.x * 256 + threadIdx.x;
    if (i >= L * NCOMB) return;
    float s = 0.f;
    #pragma unroll
    for (int j = 0; j < G2_S; ++j)
        s += part[(size_t)j * L * NCOMB + i];
    dtbc[i] = s;
}

// ---------------------------------------------------------------------------
// dt = softplus(dtr @ dtw^T + dtb), stored bf16. Block = 256 ch x 32 t.
// ---------------------------------------------------------------------------
__global__ __launch_bounds__(256)
void dt_k(const float* __restrict__ dtbc, const float* __restrict__ dtw,
          const float* __restrict__ dtb, u16* __restrict__ dt)
{
    __shared__ float dtr_s[32][48];
    const int tid = threadIdx.x;
    const int d   = blockIdx.x * 256 + tid;
    const int t0  = blockIdx.y * 32;

    for (int i = tid; i < 384; i += 256) {
        const int r = i / 12, c = (i - r * 12) * 4;
        const float4 v = *(const float4*)(dtbc + (size_t)(t0 + r) * NCOMB + c);
        *(float4*)&dtr_s[r][c] = v;
    }
    __syncthreads();

    float w[48];
    #pragma unroll
    for (int j = 0; j < 12; ++j) {
        const float4 v = *(const float4*)(dtw + (size_t)d * DR + j * 4);
        w[j * 4 + 0] = v.x; w[j * 4 + 1] = v.y;
        w[j * 4 + 2] = v.z; w[j * 4 + 3] = v.w;
    }
    const float b = dtb[d];

    for (int t = 0; t < 32; ++t) {
        float s = b;
        #pragma unroll
        for (int j = 0; j < 12; ++j) {
            const float4 v = *(const float4*)&dtr_s[t][j * 4];
            s = fmaf(v.x, w[j * 4 + 0], s);
            s = fmaf(v.y, w[j * 4 + 1], s);
            s = fmaf(v.z, w[j * 4 + 2], s);
            s = fmaf(v.w, w[j * 4 + 3], s);
        }
        dt[(size_t)(t0 + t) * DI + d] = f2bf(softplus_f(s));
    }
}

// ---------------------------------------------------------------------------
// Fused 3-phase selective scan (cooperative launch, grid (6,128), 768 blocks,
// 3 blocks/CU). Per block: chunk c (32 ts) x 256 channels. dt/x parked in LDS
// across grid syncs so phase 3 replays with ZERO HBM re-read of dt/xcv.
// B/C read as wave-uniform s_loads from L2-resident dtbc (no staging barrier).
// ---------------------------------------------------------------------------
namespace cg = cooperative_groups;

__global__ __launch_bounds__(256)
void scan_fused_k(const u16* __restrict__ dt, const float* __restrict__ xcv,
                  const float* __restrict__ dtbc, const float* __restrict__ Aneg,
                  const float* __restrict__ Dp, const float* __restrict__ xz,
                  u16* __restrict__ ybf, u16* hc, float* __restrict__ Ssum)
{
    __shared__ float xs[CH][256];    // 32 KB
    __shared__ u16   dts[CH][256];   // 16 KB   (total 48 KB -> 3 blocks/CU)

    cg::grid_group grid = cg::this_grid();

    const int tid = threadIdx.x;
    const int cb  = blockIdx.x;            // 0..5 channel block
    const int c   = blockIdx.y;            // 0..127 chunk
    const int d   = cb * 256 + tid;

    float Ad[DS], h[DS];
    #pragma unroll
    for (int q = 0; q < 4; ++q)
        *(float4*)&Ad[q * 4] = *(const float4*)(Aneg + (size_t)d * DS + q * 4);
    #pragma unroll
    for (int n = 0; n < DS; ++n) h[n] = 0.f;

    // ---- Phase 1: local chunk scan; park dt/x in LDS ----
    {
        size_t base = (size_t)(c * CH) * DI + d;
        float S = 0.f;
        for (int tt = 0; tt < CH; ++tt, base += DI) {
            const u16  draw = dt[base];
            const float xv  = xcv[base];
            dts[tt][tid] = draw;
            xs[tt][tid]  = xv;
            const float dtv = bf2f(draw);
            S += dtv;
            const float xdt = xv * dtv;
            const float* brow = dtbc + (size_t)(c * CH + tt) * NCOMB + 48;
            #pragma unroll
            for (int q = 0; q < 4; ++q) {
                const float4 bq = *(const float4*)(brow + q * 4);
                h[q * 4 + 0] = fmaf(h[q * 4 + 0], __expf(Ad[q * 4 + 0] * dtv), xdt * bq.x);
                h[q * 4 + 1] = fmaf(h[q * 4 + 1], __expf(Ad[q * 4 + 1] * dtv), xdt * bq.y);
                h[q * 4 + 2] = fmaf(h[q * 4 + 2], __expf(Ad[q * 4 + 2] * dtv), xdt * bq.z);
                h[q * 4 + 3] = fmaf(h[q * 4 + 3], __expf(Ad[q * 4 + 3] * dtv), xdt * bq.w);
            }
        }
        u16* o = hc + ((size_t)c * DI + d) * DS;
        #pragma unroll
        for (int q = 0; q < 4; ++q) {
            ushort4 pk;
            pk.x = f2bf(h[q * 4 + 0]); pk.y = f2bf(h[q * 4 + 1]);
            pk.z = f2bf(h[q * 4 + 2]); pk.w = f2bf(h[q * 4 + 3]);
            *(ushort4*)(o + q * 4) = pk;
        }
        Ssum[(size_t)c * DI + d] = S;
    }

    __threadfence();
    grid.sync();

    // ---- Phase 2: carry scan over NC chunks (blocks c<16 only) ----
    if (c < 16) {
        const int p = (c * 6 + cb) * 256 + tid;    // 0..24575 = DI*DS
        const int d2 = p >> 4;
        const float Ad2 = Aneg[p];
        float h2 = 0.f;
        for (int cc = 0; cc < NC; ++cc) {
            const size_t o = (size_t)cc * DI * DS + p;
            const float hl = bf2f(hc[o]);   // local state
            hc[o] = f2bf(h2);               // overwrite with carry-in
            h2 = fmaf(h2, __expf(Ad2 * Ssum[(size_t)cc * DI + d2]), hl);
        }
    }

    __threadfence();
    grid.sync();

    // ---- Phase 3: replay from LDS with carry-in; emit yz bf16 ----
    {
        const u16* co = hc + ((size_t)c * DI + d) * DS;
        #pragma unroll
        for (int q = 0; q < 4; ++q) {
            const ushort4 cv = *(const ushort4*)(co + q * 4);
            h[q * 4 + 0] = bf2f(cv.x); h[q * 4 + 1] = bf2f(cv.y);
            h[q * 4 + 2] = bf2f(cv.z); h[q * 4 + 3] = bf2f(cv.w);
        }
        const float Dv = Dp[d];

        int t = c * CH;
        for (int tt = 0; tt < CH; ++tt, ++t) {
            const float dtv = bf2f(dts[tt][tid]);
            const float xv  = xs[tt][tid];
            const float xdt = xv * dtv;
            float y = Dv * xv;
            const float* brow = dtbc + (size_t)(c * CH + tt) * NCOMB + 48;
            const float* crow = brow + 16;
            #pragma unroll
            for (int q = 0; q < 4; ++q) {
                const float4 bq = *(const float4*)(brow + q * 4);
                const float4 cq = *(const float4*)(crow + q * 4);
                h[q * 4 + 0] = fmaf(h[q * 4 + 0], __expf(Ad[q * 4 + 0] * dtv), xdt * bq.x);
                h[q * 4 + 1] = fmaf(h[q * 4 + 1], __expf(Ad[q * 4 + 1] * dtv), xdt * bq.y);
                h[q * 4 + 2] = fmaf(h[q * 4 + 2], __expf(Ad[q * 4 + 2] * dtv), xdt * bq.z);
                h[q * 4 + 3] = fmaf(h[q * 4 + 3], __expf(Ad[q * 4 + 3] * dtv), xdt * bq.w);
                y = fmaf(h[q * 4 + 0], cq.x, y);
                y = fmaf(h[q * 4 + 1], cq.y, y);
                y = fmaf(h[q * 4 + 2], cq.z, y);
                y = fmaf(h[q * 4 + 3], cq.w, y);
            }
            const float z = xz[(size_t)t * (2 * DI) + DI + d];
            ybf[(size_t)t * XZROW + d] = f2bf(y * silu_f(z));
        }
    }
}

// ---------------------------------------------------------------------------
extern "C" void kernel_launch(void* const* d_in, const int* in_sizes, int n_in,
                              void* d_out, int out_size, void* d_ws, size_t ws_size,
                              hipStream_t stream)
{
    const float* u    = (const float*)d_in[0];
    const float* Wip  = (const float*)d_in[1];
    const float* cw   = (const float*)d_in[2];
    const float* cb   = (const float*)d_in[3];
    const float* xdt  = (const float*)d_in[4];
    const float* xbw  = (const float*)d_in[5];
    const float* xcw  = (const float*)d_in[6];
    const float* dtw  = (const float*)d_in[7];
    const float* dtb  = (const float*)d_in[8];
    const float* alog = (const float*)d_in[9];
    const float* Dp   = (const float*)d_in[10];
    const float* Wop  = (const float*)d_in[11];
    float* out = (float*)d_out;

    // workspace layout (floats) — ~110 MB
    float* ws   = (float*)d_ws;
    float* xz   = ws;                                // L*2*DI      = 12,582,912
    float* xcv  = xz   + (size_t)L * 2 * DI;         // L*DI        =  6,291,456
    float* dtbc = xcv  + (size_t)L * DI;             // L*NCOMB     =    327,680
    float* dty  = dtbc + (size_t)L * NCOMB;          // L*DI region (g2p, then dt bf16)
    float* Wt   = dty  + (size_t)L * DI;             // DI*NCOMB    =    122,880
    u16*   hc   = (u16*)(Wt + (size_t)DI * NCOMB);   // NC*DI*DS u16 = 1,572,864 fl
    float* Ssum = Wt + (size_t)DI * NCOMB
                     + (size_t)NC * DI * DS / 2;     // NC*DI       =    196,608
    float* Aneg = Ssum + (size_t)NC * DI;            // DI*DS       =     24,576

    // aliases into regions dead at time of use
    u16*   ubf  = (u16*)xcv;                   // [4096][768]  (dead after GEMM1)
    u16*   Wipb = (u16*)xcv + (size_t)L * DM;  // [3072][768]  (dead after GEMM1)
    float* g2p  = dty;                         // [16][4096][80] (dead after reduce)
    u16*   dtbf = (u16*)dty;                   // [4096][1536] bf16 dt (after reduce)
    u16*   xzu  = (u16*)xz;                    // x-half of xz rows: ybf + wopb

    const dim3 blk(256);

    // 1) early packs (+ Aneg precompute)
    pack_early_k<<<(NU4 + NW4 + NWT + NA + 255) / 256, blk, 0, stream>>>(
        u, Wip, xdt, xbw, xcw, alog, ubf, Wipb, Wt, Aneg);

    // 2) xz = u @ in_proj_w^T   [4096, 3072]  (bf16 MFMA, K=768)
    gemm_bf16_bt<<<dim3((2 * DI) / 128, L / 128), blk, 0, stream>>>(
        ubf, Wipb, xz, L, 2 * DI, DM);

    // 3) causal conv + SiLU -> xcv
    conv_silu_v4<<<(L * (DI / 4) + 255) / 256, blk, 0, stream>>>(xz, cw, cb, xcv);

    // 4) Wop -> bf16 into dead x-half of xz
    pack_wop_k<<<(NO4 + 255) / 256, blk, 0, stream>>>(Wop, xzu);

    // 5) [dt_rank|B|C] = xcv @ Wt via split-K (partials in dty region)
    gemm2_splitk<<<dim3(L / 64, G2_S), blk, 0, stream>>>(xcv, Wt, g2p);
    gemm2_reduce<<<(L * NCOMB + 255) / 256, blk, 0, stream>>>(g2p, dtbc);

    // 6) dt = softplus(dtr @ dtw^T + dtb) -> bf16 (overwrites g2p region)
    dt_k<<<dim3(DI / 256, L / 32), blk, 0, stream>>>(dtbc, dtw, dtb, dtbf);

    // 7) fused cooperative 3-phase scan (CH=32, 128 chunks, 768 blocks)
    {
        const u16*   a0 = dtbf;
        const float* a1 = xcv;
        const float* a2 = dtbc;
        const float* a3 = Aneg;
        const float* a4 = Dp;
        const float* a5 = xz;
        u16*         a6 = xzu;
        u16*         a7 = hc;
        float*       a8 = Ssum;
        void* kargs[] = { &a0, &a1, &a2, &a3, &a4, &a5, &a6, &a7, &a8 };
        hipLaunchCooperativeKernel((void*)scan_fused_k,
                                   dim3(DI / 256, NC), blk, kargs, 0, stream);
    }

    // 8) out = yz @ out_proj_w^T   [4096, 768]  (bf16 MFMA, strided rows)
    gemm_bf16_bt_n64<<<dim3(DM / 64, L / 128), blk, 0, stream>>>(
        xzu, XZROW, xzu + 1536, XZROW, out, L, DM, DI);
}

// Round 11
// 237.291 us; speedup vs baseline: 2.3897x; 2.3897x over previous
//
#include <hip/hip_runtime.h>
#include <math.h>

// Problem constants (UnifiedMambaBlock, B=1)
#define L      4096
#define DM     768
#define DI     1536
#define DS     16
#define DR     48
#define NCOMB  80     // 48 dt_rank + 16 B + 16 C
#define CH     32     // scan chunk length
#define NC     128    // number of chunks (L / CH)
#define G2_S   16     // GEMM2 K-splits
#define G2_KC  96     // 1536 / 16
#define XZROW  6144   // xz row stride in u16 (3072 floats)

typedef unsigned short u16;
typedef unsigned int   u32;
typedef __attribute__((ext_vector_type(8))) short bf16x8;   // 8 bf16 = 4 VGPRs
typedef __attribute__((ext_vector_type(4))) float f32x4;

__device__ __forceinline__ float silu_f(float v) { return v / (1.f + __expf(-v)); }

__device__ __forceinline__ u16 f2bf(float f) {              // RNE f32 -> bf16
    u32 u = __float_as_uint(f);
    return (u16)((u + 0x7fffu + ((u >> 16) & 1u)) >> 16);
}
__device__ __forceinline__ float bf2f(u16 h) {
    return __uint_as_float(((u32)h) << 16);
}

__device__ __forceinline__ float softplus_f(float s) {
    return (s > 20.f) ? s : log1pf(expf(s));
}

__device__ __forceinline__ void gl_lds16(const u16* g, u16* l) {
    __builtin_amdgcn_global_load_lds(
        (const __attribute__((address_space(1))) void*)g,
        (__attribute__((address_space(3))) void*)l, 16, 0, 0);
}

// ---------------------------------------------------------------------------
// bf16 MFMA GEMM (m97 structure): C[M,N] fp32 = A[M,K] @ W[N,K]^T, bf16 in.
// 128x128 tile, BK=32, 256 threads (4 waves, 2x2 of 64x64), double-buffer LDS.
// ---------------------------------------------------------------------------
__global__ __launch_bounds__(256)
void gemm_bf16_bt(const u16* __restrict__ A, const u16* __restrict__ W,
                  float* __restrict__ C, int M, int N, int K)
{
    __shared__ u16 As[2][128 * 32];
    __shared__ u16 Bs[2][128 * 32];

    const int tid  = threadIdx.x;
    const int lane = tid & 63;
    const int wave = tid >> 6;
    const int wr   = (wave >> 1) * 64;
    const int wc   = (wave & 1) * 64;
    const int m0   = blockIdx.y * 128;
    const int n0   = blockIdx.x * 128;

    const int r0 = tid >> 2;
    const int k0 = (tid & 3) * 8;

    const int frow = lane & 15;
    const int fk   = (lane >> 4) * 8;

    f32x4 acc[4][4];
    #pragma unroll
    for (int i = 0; i < 4; ++i)
        #pragma unroll
        for (int j = 0; j < 4; ++j)
            acc[i][j] = (f32x4){0.f, 0.f, 0.f, 0.f};

    const int NT = K >> 5;

#define STAGE(buf, kk) {                                                       \
        const u16* ga = A + (size_t)(m0 + r0) * K + (kk) + k0;                 \
        const u16* gw = W + (size_t)(n0 + r0) * K + (kk) + k0;                 \
        gl_lds16(ga,                   &As[buf][tid * 8]);                     \
        gl_lds16(ga + (size_t)64 * K,  &As[buf][2048 + tid * 8]);              \
        gl_lds16(gw,                   &Bs[buf][tid * 8]);                     \
        gl_lds16(gw + (size_t)64 * K,  &Bs[buf][2048 + tid * 8]); }

    STAGE(0, 0);
    __syncthreads();

    for (int t = 0; t < NT; ++t) {
        const int b = t & 1;
        if (t + 1 < NT) STAGE(b ^ 1, (t + 1) << 5);

        bf16x8 af[4], bw[4];
        #pragma unroll
        for (int m = 0; m < 4; ++m)
            af[m] = *(const bf16x8*)&As[b][(wr + m * 16 + frow) * 32 + fk];
        #pragma unroll
        for (int n = 0; n < 4; ++n)
            bw[n] = *(const bf16x8*)&Bs[b][(wc + n * 16 + frow) * 32 + fk];

        #pragma unroll
        for (int m = 0; m < 4; ++m)
            #pragma unroll
            for (int n = 0; n < 4; ++n)
                acc[m][n] = __builtin_amdgcn_mfma_f32_16x16x32_bf16(
                    af[m], bw[n], acc[m][n], 0, 0, 0);

        __syncthreads();
    }
#undef STAGE

    const int crow = (lane >> 4) * 4;
    const int ccol = lane & 15;
    #pragma unroll
    for (int m = 0; m < 4; ++m)
        #pragma unroll
        for (int n = 0; n < 4; ++n)
            #pragma unroll
            for (int r = 0; r < 4; ++r)
                C[(size_t)(m0 + wr + m * 16 + crow + r) * N
                  + n0 + wc + n * 16 + ccol] = acc[m][n][r];
}

// ---------------------------------------------------------------------------
// bf16 MFMA GEMM with strided rows (lda/ldw in u16 elems), 128(M)x64(N) tile.
// ---------------------------------------------------------------------------
__global__ __launch_bounds__(256)
void gemm_bf16_bt_n64(const u16* __restrict__ A, int lda,
                      const u16* __restrict__ W, int ldw,
                      float* __restrict__ C, int M, int N, int K)
{
    __shared__ u16 As[2][128 * 32];
    __shared__ u16 Bs[2][64 * 32];

    const int tid  = threadIdx.x;
    const int lane = tid & 63;
    const int wave = tid >> 6;
    const int wr   = (wave >> 1) * 64;
    const int wc   = (wave & 1) * 32;
    const int m0   = blockIdx.y * 128;
    const int n0   = blockIdx.x * 64;

    const int r0 = tid >> 2;
    const int k0 = (tid & 3) * 8;

    const int frow = lane & 15;
    const int fk   = (lane >> 4) * 8;

    f32x4 acc[4][2];
    #pragma unroll
    for (int i = 0; i < 4; ++i)
        #pragma unroll
        for (int j = 0; j < 2; ++j)
            acc[i][j] = (f32x4){0.f, 0.f, 0.f, 0.f};

    const int NT = K >> 5;

#define STG(buf, kk) {                                                         \
        const u16* ga = A + (size_t)(m0 + r0) * lda + (kk) + k0;               \
        gl_lds16(ga,                     &As[buf][tid * 8]);                   \
        gl_lds16(ga + (size_t)64 * lda,  &As[buf][2048 + tid * 8]);            \
        gl_lds16(W + (size_t)(n0 + r0) * ldw + (kk) + k0, &Bs[buf][tid * 8]); }

    STG(0, 0);
    __syncthreads();

    for (int t = 0; t < NT; ++t) {
        const int b = t & 1;
        if (t + 1 < NT) STG(b ^ 1, (t + 1) << 5);

        bf16x8 af[4], bw[2];
        #pragma unroll
        for (int m = 0; m < 4; ++m)
            af[m] = *(const bf16x8*)&As[b][(wr + m * 16 + frow) * 32 + fk];
        #pragma unroll
        for (int n = 0; n < 2; ++n)
            bw[n] = *(const bf16x8*)&Bs[b][(wc + n * 16 + frow) * 32 + fk];

        #pragma unroll
        for (int m = 0; m < 4; ++m)
            #pragma unroll
            for (int n = 0; n < 2; ++n)
                acc[m][n] = __builtin_amdgcn_mfma_f32_16x16x32_bf16(
                    af[m], bw[n], acc[m][n], 0, 0, 0);

        __syncthreads();
    }
#undef STG

    const int crow = (lane >> 4) * 4;
    const int ccol = lane & 15;
    #pragma unroll
    for (int m = 0; m < 4; ++m)
        #pragma unroll
        for (int n = 0; n < 2; ++n)
            #pragma unroll
            for (int r = 0; r < 4; ++r)
                C[(size_t)(m0 + wr + m * 16 + crow + r) * N
                  + n0 + wc + n * 16 + ccol] = acc[m][n][r];
}

// ---------------------------------------------------------------------------
// Early pack: u -> ubf, Wip -> Wipb (bf16), [xdt;xb;xc]^T -> Wt (fp32),
// Aneg = -exp(A_log)
// ---------------------------------------------------------------------------
#define NU4  (L * DM / 4)            // 786432
#define NW4  (2 * DI * DM / 4)       // 589824
#define NWT  (DI * NCOMB)            // 122880
#define NA   (DI * DS)               // 24576
__global__ __launch_bounds__(256)
void pack_early_k(const float* __restrict__ u, const float* __restrict__ Wip,
                  const float* __restrict__ xdt, const float* __restrict__ xb,
                  const float* __restrict__ xc, const float* __restrict__ alog,
                  u16* __restrict__ ubf, u16* __restrict__ Wipb,
                  float* __restrict__ Wt, float* __restrict__ Aneg)
{
    int i = blockIdx.x * 256 + threadIdx.x;
    if (i < NU4) {
        const float4 v = ((const float4*)u)[i];
        ushort4 o; o.x = f2bf(v.x); o.y = f2bf(v.y); o.z = f2bf(v.z); o.w = f2bf(v.w);
        ((ushort4*)ubf)[i] = o;
        return;
    }
    i -= NU4;
    if (i < NW4) {
        const float4 v = ((const float4*)Wip)[i];
        ushort4 o; o.x = f2bf(v.x); o.y = f2bf(v.y); o.z = f2bf(v.z); o.w = f2bf(v.w);
        ((ushort4*)Wipb)[i] = o;
        return;
    }
    i -= NW4;
    if (i < NWT) {
        const int k = i / NCOMB, n = i - k * NCOMB;
        float v;
        if (n < 48)      v = xdt[n * DI + k];
        else if (n < 64) v = xb[(n - 48) * DI + k];
        else             v = xc[(n - 64) * DI + k];
        Wt[i] = v;
        return;
    }
    i -= NWT;
    if (i < NA)
        Aneg[i] = -expf(alog[i]);
}

// ---------------------------------------------------------------------------
// Wop -> bf16, scattered into dead x-half of xz rows (row r, u16 cols 1536+c)
// ---------------------------------------------------------------------------
#define NO4  (DM * DI / 4)           // 294912
__global__ __launch_bounds__(256)
void pack_wop_k(const float* __restrict__ Wop, u16* __restrict__ xzu)
{
    int i = blockIdx.x * 256 + threadIdx.x;
    if (i >= NO4) return;
    const float4 v = ((const float4*)Wop)[i];
    ushort4 o; o.x = f2bf(v.x); o.y = f2bf(v.y); o.z = f2bf(v.z); o.w = f2bf(v.w);
    const int e = i * 4;
    const int r = e / DI, c = e - r * DI;
    *(ushort4*)(xzu + (size_t)r * XZROW + 1536 + c) = o;
}

// ---------------------------------------------------------------------------
// Vectorized causal depthwise conv (width 4) + bias + SiLU: 4 channels/thread
// ---------------------------------------------------------------------------
__global__ __launch_bounds__(256)
void conv_silu_v4(const float* __restrict__ xz, const float* __restrict__ cw,
                  const float* __restrict__ cb, float* __restrict__ xcv)
{
    int idx = blockIdx.x * 256 + threadIdx.x;
    if (idx >= L * (DI / 4)) return;
    const int t = idx / (DI / 4);
    const int q = idx - t * (DI / 4);
    const int d = q * 4;

    const float4 w0 = ((const float4*)cw)[d + 0];
    const float4 w1 = ((const float4*)cw)[d + 1];
    const float4 w2 = ((const float4*)cw)[d + 2];
    const float4 w3 = ((const float4*)cw)[d + 3];
    float4 acc = ((const float4*)cb)[q];

    const float* base = xz + d;
    #pragma unroll
    for (int j = 0; j < 4; ++j) {
        const int tt = t - 3 + j;
        if (tt >= 0) {
            const float4 x = *(const float4*)(base + (size_t)tt * (2 * DI));
            acc.x = fmaf(((const float*)&w0)[j], x.x, acc.x);
            acc.y = fmaf(((const float*)&w1)[j], x.y, acc.y);
            acc.z = fmaf(((const float*)&w2)[j], x.z, acc.z);
            acc.w = fmaf(((const float*)&w3)[j], x.w, acc.w);
        }
    }
    float4 o;
    o.x = silu_f(acc.x); o.y = silu_f(acc.y);
    o.z = silu_f(acc.z); o.w = silu_f(acc.w);
    ((float4*)xcv)[idx] = o;
}

// ---------------------------------------------------------------------------
// GEMM2 split-K: part[s][L][80] = xcv[L][DI-slice] @ Wt[DI-slice][80]
// ---------------------------------------------------------------------------
__global__ __launch_bounds__(256)
void gemm2_splitk(const float* __restrict__ A, const float* __restrict__ Wt,
                  float* __restrict__ part)
{
    __shared__ float As[G2_KC][65];     // +1 pad
    __shared__ float Ws[G2_KC][80];

    const int tid  = threadIdx.x;
    const int m0   = blockIdx.x * 64;
    const int koff = blockIdx.y * G2_KC;

    {
        const int r = tid >> 2, cg = tid & 3;
        #pragma unroll
        for (int j = 0; j < 6; ++j) {
            const int kk = (j * 4 + cg) * 4;
            const float4 v = *(const float4*)(A + (size_t)(m0 + r) * DI + koff + kk);
            As[kk + 0][r] = v.x; As[kk + 1][r] = v.y;
            As[kk + 2][r] = v.z; As[kk + 3][r] = v.w;
        }
    }
    for (int i = tid; i < G2_KC * 80; i += 256)
        (&Ws[0][0])[i] = Wt[(size_t)koff * 80 + i];
    __syncthreads();

    const int g  = tid >> 6;
    const int r  = tid & 63;
    const int c0 = g * 20;

    float acc[20];
    #pragma unroll
    for (int j = 0; j < 20; ++j) acc[j] = 0.f;

    #pragma unroll 2
    for (int k = 0; k < G2_KC; ++k) {
        const float a = As[k][r];
        #pragma unroll
        for (int q = 0; q < 5; ++q) {
            const float4 w = *(const float4*)&Ws[k][c0 + q * 4];
            acc[q * 4 + 0] = fmaf(a, w.x, acc[q * 4 + 0]);
            acc[q * 4 + 1] = fmaf(a, w.y, acc[q * 4 + 1]);
            acc[q * 4 + 2] = fmaf(a, w.z, acc[q * 4 + 2]);
            acc[q * 4 + 3] = fmaf(a, w.w, acc[q * 4 + 3]);
        }
    }

    float* p = part + (size_t)blockIdx.y * (L * NCOMB)
                    + (size_t)(m0 + r) * NCOMB + c0;
    #pragma unroll
    for (int q = 0; q < 5; ++q)
        ((float4*)p)[q] = make_float4(acc[q * 4], acc[q * 4 + 1],
                                      acc[q * 4 + 2], acc[q * 4 + 3]);
}

__global__ __launch_bounds__(256)
void gemm2_reduce(const float* __restrict__ part, float* __restrict__ dtbc)
{
    int i = blockIdx.x * 256 + threadIdx.x;
    if (i >= L * NCOMB) return;
    float s = 0.f;
    #pragma unroll
    for (int j = 0; j < G2_S; ++j)
        s += part[(size_t)j * L * NCOMB + i];
    dtbc[i] = s;
}

// ---------------------------------------------------------------------------
// dt = softplus(dtr @ dtw^T + dtb), stored bf16. Block = 256 ch x 32 t.
// ---------------------------------------------------------------------------
__global__ __launch_bounds__(256)
void dt_k(const float* __restrict__ dtbc, const float* __restrict__ dtw,
          const float* __restrict__ dtb, u16* __restrict__ dt)
{
    __shared__ float dtr_s[32][48];
    const int tid = threadIdx.x;
    const int d   = blockIdx.x * 256 + tid;
    const int t0  = blockIdx.y * 32;

    for (int i = tid; i < 384; i += 256) {
        const int r = i / 12, c = (i - r * 12) * 4;
        const float4 v = *(const float4*)(dtbc + (size_t)(t0 + r) * NCOMB + c);
        *(float4*)&dtr_s[r][c] = v;
    }
    __syncthreads();

    float w[48];
    #pragma unroll
    for (int j = 0; j < 12; ++j) {
        const float4 v = *(const float4*)(dtw + (size_t)d * DR + j * 4);
        w[j * 4 + 0] = v.x; w[j * 4 + 1] = v.y;
        w[j * 4 + 2] = v.z; w[j * 4 + 3] = v.w;
    }
    const float b = dtb[d];

    for (int t = 0; t < 32; ++t) {
        float s = b;
        #pragma unroll
        for (int j = 0; j < 12; ++j) {
            const float4 v = *(const float4*)&dtr_s[t][j * 4];
            s = fmaf(v.x, w[j * 4 + 0], s);
            s = fmaf(v.y, w[j * 4 + 1], s);
            s = fmaf(v.z, w[j * 4 + 2], s);
            s = fmaf(v.w, w[j * 4 + 3], s);
        }
        dt[(size_t)(t0 + t) * DI + d] = f2bf(softplus_f(s));
    }
}

// ---------------------------------------------------------------------------
// Scan pass 1: per-chunk local states (bf16) + dt chunk-sums. CH=32.
// ---------------------------------------------------------------------------
__global__ __launch_bounds__(256)
void scan1_k(const u16* __restrict__ dt, const float* __restrict__ xcv,
             const float* __restrict__ dtbc, const float* __restrict__ Aneg,
             u16* __restrict__ hloc, float* __restrict__ Ssum)
{
    __shared__ float Bs[CH][DS];
    const int c = blockIdx.y;
    const int d = blockIdx.x * 256 + threadIdx.x;

    for (int i = threadIdx.x; i < CH * DS; i += 256) {
        int tt = i >> 4, n = i & 15;
        Bs[tt][n] = dtbc[(size_t)(c * CH + tt) * NCOMB + 48 + n];
    }
    __syncthreads();

    float Ad[DS], h[DS];
    #pragma unroll
    for (int q = 0; q < 4; ++q)
        *(float4*)&Ad[q * 4] = *(const float4*)(Aneg + (size_t)d * DS + q * 4);
    #pragma unroll
    for (int n = 0; n < DS; ++n) h[n] = 0.f;

    size_t base = (size_t)(c * CH) * DI + d;
    float S = 0.f;
    for (int tt = 0; tt < CH; ++tt, base += DI) {
        const float dtv = bf2f(dt[base]);
        const float xv  = xcv[base];
        S += dtv;
        const float xdt = xv * dtv;
        #pragma unroll
        for (int n = 0; n < DS; ++n)
            h[n] = fmaf(h[n], __expf(Ad[n] * dtv), xdt * Bs[tt][n]);
    }

    u16* o = hloc + ((size_t)c * DI + d) * DS;
    #pragma unroll
    for (int q = 0; q < 4; ++q) {
        ushort4 pk;
        pk.x = f2bf(h[q * 4 + 0]); pk.y = f2bf(h[q * 4 + 1]);
        pk.z = f2bf(h[q * 4 + 2]); pk.w = f2bf(h[q * 4 + 3]);
        *(ushort4*)(o + q * 4) = pk;
    }
    Ssum[c * DI + d] = S;
}

// ---------------------------------------------------------------------------
// Scan pass 2: scan the NC chunk carries per (d,n); hc bf16 in-place.
// ---------------------------------------------------------------------------
__global__ __launch_bounds__(256)
void scan2_k(u16* hc, const float* __restrict__ Ssum,
             const float* __restrict__ Aneg)
{
    const int p = blockIdx.x * 256 + threadIdx.x;
    if (p >= DI * DS) return;
    const int d = p >> 4;
    const float Ad = Aneg[p];
    float h = 0.f;
    for (int c = 0; c < NC; ++c) {
        const size_t o = (size_t)c * DI * DS + p;
        const float hl = bf2f(hc[o]);     // local state
        hc[o] = f2bf(h);                  // overwrite with carry-in
        h = fmaf(h, __expf(Ad * Ssum[c * DI + d]), hl);
    }
}

// ---------------------------------------------------------------------------
// Scan pass 3: replay with carry-in; emit yz bf16 into dead x-half of xz.
// ---------------------------------------------------------------------------
__global__ __launch_bounds__(256)
void scan3_k(const u16* __restrict__ dt, const float* __restrict__ xcv,
             const float* __restrict__ dtbc, const float* __restrict__ Aneg,
             const u16* __restrict__ carry, const float* __restrict__ Dp,
             const float* __restrict__ xz, u16* __restrict__ ybf)
{
    __shared__ float Bs[CH][DS];
    __shared__ float Cs[CH][DS];
    const int c = blockIdx.y;
    const int d = blockIdx.x * 256 + threadIdx.x;

    for (int i = threadIdx.x; i < CH * DS; i += 256) {
        int tt = i >> 4, n = i & 15;
        Bs[tt][n] = dtbc[(size_t)(c * CH + tt) * NCOMB + 48 + n];
        Cs[tt][n] = dtbc[(size_t)(c * CH + tt) * NCOMB + 64 + n];
    }
    __syncthreads();

    float Ad[DS], h[DS];
    const u16* co = carry + ((size_t)c * DI + d) * DS;
    #pragma unroll
    for (int q = 0; q < 4; ++q) {
        const ushort4 cv = *(const ushort4*)(co + q * 4);
        h[q * 4 + 0] = bf2f(cv.x); h[q * 4 + 1] = bf2f(cv.y);
        h[q * 4 + 2] = bf2f(cv.z); h[q * 4 + 3] = bf2f(cv.w);
    }
    #pragma unroll
    for (int q = 0; q < 4; ++q)
        *(float4*)&Ad[q * 4] = *(const float4*)(Aneg + (size_t)d * DS + q * 4);
    const float Dv = Dp[d];

    int t = c * CH;
    for (int tt = 0; tt < CH; ++tt, ++t) {
        const size_t o = (size_t)t * DI + d;
        const float dtv = bf2f(dt[o]);
        const float xv  = xcv[o];
        const float xdt = xv * dtv;
        float y = Dv * xv;
        #pragma unroll
        for (int n = 0; n < DS; ++n) {
            h[n] = fmaf(h[n], __expf(Ad[n] * dtv), xdt * Bs[tt][n]);
            y = fmaf(h[n], Cs[tt][n], y);
        }
        const float z = xz[(size_t)t * (2 * DI) + DI + d];
        ybf[(size_t)t * XZROW + d] = f2bf(y * silu_f(z));
    }
}

// ---------------------------------------------------------------------------
extern "C" void kernel_launch(void* const* d_in, const int* in_sizes, int n_in,
                              void* d_out, int out_size, void* d_ws, size_t ws_size,
                              hipStream_t stream)
{
    const float* u    = (const float*)d_in[0];
    const float* Wip  = (const float*)d_in[1];
    const float* cw   = (const float*)d_in[2];
    const float* cb   = (const float*)d_in[3];
    const float* xdt  = (const float*)d_in[4];
    const float* xbw  = (const float*)d_in[5];
    const float* xcw  = (const float*)d_in[6];
    const float* dtw  = (const float*)d_in[7];
    const float* dtb  = (const float*)d_in[8];
    const float* alog = (const float*)d_in[9];
    const float* Dp   = (const float*)d_in[10];
    const float* Wop  = (const float*)d_in[11];
    float* out = (float*)d_out;

    // workspace layout (floats) — ~110 MB
    float* ws   = (float*)d_ws;
    float* xz   = ws;                                // L*2*DI      = 12,582,912
    float* xcv  = xz   + (size_t)L * 2 * DI;         // L*DI        =  6,291,456
    float* dtbc = xcv  + (size_t)L * DI;             // L*NCOMB     =    327,680
    float* dty  = dtbc + (size_t)L * NCOMB;          // L*DI region (g2p, then dt bf16)
    float* Wt   = dty  + (size_t)L * DI;             // DI*NCOMB    =    122,880
    u16*   hc   = (u16*)(Wt + (size_t)DI * NCOMB);   // NC*DI*DS u16 = 1,572,864 fl
    float* Ssum = Wt + (size_t)DI * NCOMB
                     + (size_t)NC * DI * DS / 2;     // NC*DI       =    196,608
    float* Aneg = Ssum + (size_t)NC * DI;            // DI*DS       =     24,576

    // aliases into regions dead at time of use
    u16*   ubf  = (u16*)xcv;                   // [4096][768]  (dead after GEMM1)
    u16*   Wipb = (u16*)xcv + (size_t)L * DM;  // [3072][768]  (dead after GEMM1)
    float* g2p  = dty;                         // [16][4096][80] (dead after reduce)
    u16*   dtbf = (u16*)dty;                   // [4096][1536] bf16 dt (after reduce)
    u16*   xzu  = (u16*)xz;                    // x-half of xz rows: ybf + wopb

    const dim3 blk(256);

    // 1) early packs (+ Aneg precompute)
    pack_early_k<<<(NU4 + NW4 + NWT + NA + 255) / 256, blk, 0, stream>>>(
        u, Wip, xdt, xbw, xcw, alog, ubf, Wipb, Wt, Aneg);

    // 2) xz = u @ in_proj_w^T   [4096, 3072]  (bf16 MFMA, K=768)
    gemm_bf16_bt<<<dim3((2 * DI) / 128, L / 128), blk, 0, stream>>>(
        ubf, Wipb, xz, L, 2 * DI, DM);

    // 3) causal conv + SiLU -> xcv
    conv_silu_v4<<<(L * (DI / 4) + 255) / 256, blk, 0, stream>>>(xz, cw, cb, xcv);

    // 4) Wop -> bf16 into dead x-half of xz
    pack_wop_k<<<(NO4 + 255) / 256, blk, 0, stream>>>(Wop, xzu);

    // 5) [dt_rank|B|C] = xcv @ Wt via split-K (partials in dty region)
    gemm2_splitk<<<dim3(L / 64, G2_S), blk, 0, stream>>>(xcv, Wt, g2p);
    gemm2_reduce<<<(L * NCOMB + 255) / 256, blk, 0, stream>>>(g2p, dtbc);

    // 6) dt = softplus(dtr @ dtw^T + dtb) -> bf16 (overwrites g2p region)
    dt_k<<<dim3(DI / 256, L / 32), blk, 0, stream>>>(dtbc, dtw, dtb, dtbf);

    // 7-9) chunked selective scan (CH=32, 128 chunks)
    scan1_k<<<dim3(DI / 256, NC), blk, 0, stream>>>(
        dtbf, xcv, dtbc, Aneg, hc, Ssum);
    scan2_k<<<(DI * DS) / 256, blk, 0, stream>>>(hc, Ssum, Aneg);
    scan3_k<<<dim3(DI / 256, NC), blk, 0, stream>>>(
        dtbf, xcv, dtbc, Aneg, hc, Dp, xz, xzu);

    // 10) out = yz @ out_proj_w^T   [4096, 768]  (bf16 MFMA, strided rows)
    gemm_bf16_bt_n64<<<dim3(DM / 64, L / 128), blk, 0, stream>>>(
        xzu, XZROW, xzu + 1536, XZROW, out, L, DM, DI);
}

// Round 12
// 230.909 us; speedup vs baseline: 2.4558x; 1.0276x over previous
//
#include <hip/hip_runtime.h>
#include <math.h>

// Problem constants (UnifiedMambaBlock, B=1)
#define L      4096
#define DM     768
#define DI     1536
#define DS     16
#define DR     48
#define NCOMB  80     // 48 dt_rank + 16 B + 16 C
#define CH     32     // scan chunk length
#define NC     128    // number of chunks (L / CH)
#define G2_S   16     // GEMM2 K-splits
#define G2_KC  96     // 1536 / 16
#define XZROW  3072   // xz row stride in u16 (bf16 [4096][3072])

typedef unsigned short u16;
typedef unsigned int   u32;
typedef __attribute__((ext_vector_type(8))) short bf16x8;   // 8 bf16 = 4 VGPRs
typedef __attribute__((ext_vector_type(4))) float f32x4;

__device__ __forceinline__ float silu_f(float v) { return v / (1.f + __expf(-v)); }

__device__ __forceinline__ u16 f2bf(float f) {              // RNE f32 -> bf16
    u32 u = __float_as_uint(f);
    return (u16)((u + 0x7fffu + ((u >> 16) & 1u)) >> 16);
}
__device__ __forceinline__ float bf2f(u16 h) {
    return __uint_as_float(((u32)h) << 16);
}

__device__ __forceinline__ float softplus_f(float s) {
    return (s > 20.f) ? s : log1pf(expf(s));
}

__device__ __forceinline__ void gl_lds16(const u16* g, u16* l) {
    __builtin_amdgcn_global_load_lds(
        (const __attribute__((address_space(1))) void*)g,
        (__attribute__((address_space(3))) void*)l, 16, 0, 0);
}

// ---------------------------------------------------------------------------
// bf16 MFMA GEMM (m97 structure), BF16 OUTPUT: Cb[M][N] bf16 = A @ W^T.
// 128x128 tile, BK=32, 256 threads (4 waves, 2x2 of 64x64), double-buffer LDS.
// ---------------------------------------------------------------------------
__global__ __launch_bounds__(256)
void gemm_bf16_bt_o16(const u16* __restrict__ A, const u16* __restrict__ W,
                      u16* __restrict__ Cb, int M, int N, int K)
{
    __shared__ u16 As[2][128 * 32];
    __shared__ u16 Bs[2][128 * 32];

    const int tid  = threadIdx.x;
    const int lane = tid & 63;
    const int wave = tid >> 6;
    const int wr   = (wave >> 1) * 64;
    const int wc   = (wave & 1) * 64;
    const int m0   = blockIdx.y * 128;
    const int n0   = blockIdx.x * 128;

    const int r0 = tid >> 2;
    const int k0 = (tid & 3) * 8;

    const int frow = lane & 15;
    const int fk   = (lane >> 4) * 8;

    f32x4 acc[4][4];
    #pragma unroll
    for (int i = 0; i < 4; ++i)
        #pragma unroll
        for (int j = 0; j < 4; ++j)
            acc[i][j] = (f32x4){0.f, 0.f, 0.f, 0.f};

    const int NT = K >> 5;

#define STAGE(buf, kk) {                                                       \
        const u16* ga = A + (size_t)(m0 + r0) * K + (kk) + k0;                 \
        const u16* gw = W + (size_t)(n0 + r0) * K + (kk) + k0;                 \
        gl_lds16(ga,                   &As[buf][tid * 8]);                     \
        gl_lds16(ga + (size_t)64 * K,  &As[buf][2048 + tid * 8]);              \
        gl_lds16(gw,                   &Bs[buf][tid * 8]);                     \
        gl_lds16(gw + (size_t)64 * K,  &Bs[buf][2048 + tid * 8]); }

    STAGE(0, 0);
    __syncthreads();

    for (int t = 0; t < NT; ++t) {
        const int b = t & 1;
        if (t + 1 < NT) STAGE(b ^ 1, (t + 1) << 5);

        bf16x8 af[4], bw[4];
        #pragma unroll
        for (int m = 0; m < 4; ++m)
            af[m] = *(const bf16x8*)&As[b][(wr + m * 16 + frow) * 32 + fk];
        #pragma unroll
        for (int n = 0; n < 4; ++n)
            bw[n] = *(const bf16x8*)&Bs[b][(wc + n * 16 + frow) * 32 + fk];

        #pragma unroll
        for (int m = 0; m < 4; ++m)
            #pragma unroll
            for (int n = 0; n < 4; ++n)
                acc[m][n] = __builtin_amdgcn_mfma_f32_16x16x32_bf16(
                    af[m], bw[n], acc[m][n], 0, 0, 0);

        __syncthreads();
    }
#undef STAGE

    const int crow = (lane >> 4) * 4;
    const int ccol = lane & 15;
    #pragma unroll
    for (int m = 0; m < 4; ++m)
        #pragma unroll
        for (int n = 0; n < 4; ++n)
            #pragma unroll
            for (int r = 0; r < 4; ++r)
                Cb[(size_t)(m0 + wr + m * 16 + crow + r) * N
                   + n0 + wc + n * 16 + ccol] = f2bf(acc[m][n][r]);
}

// ---------------------------------------------------------------------------
// bf16 MFMA GEMM with strided rows (lda/ldw in u16 elems), 128(M)x64(N) tile,
// fp32 output. Used for GEMM4.
// ---------------------------------------------------------------------------
__global__ __launch_bounds__(256)
void gemm_bf16_bt_n64(const u16* __restrict__ A, int lda,
                      const u16* __restrict__ W, int ldw,
                      float* __restrict__ C, int M, int N, int K)
{
    __shared__ u16 As[2][128 * 32];
    __shared__ u16 Bs[2][64 * 32];

    const int tid  = threadIdx.x;
    const int lane = tid & 63;
    const int wave = tid >> 6;
    const int wr   = (wave >> 1) * 64;
    const int wc   = (wave & 1) * 32;
    const int m0   = blockIdx.y * 128;
    const int n0   = blockIdx.x * 64;

    const int r0 = tid >> 2;
    const int k0 = (tid & 3) * 8;

    const int frow = lane & 15;
    const int fk   = (lane >> 4) * 8;

    f32x4 acc[4][2];
    #pragma unroll
    for (int i = 0; i < 4; ++i)
        #pragma unroll
        for (int j = 0; j < 2; ++j)
            acc[i][j] = (f32x4){0.f, 0.f, 0.f, 0.f};

    const int NT = K >> 5;

#define STG(buf, kk) {                                                         \
        const u16* ga = A + (size_t)(m0 + r0) * lda + (kk) + k0;               \
        gl_lds16(ga,                     &As[buf][tid * 8]);                   \
        gl_lds16(ga + (size_t)64 * lda,  &As[buf][2048 + tid * 8]);            \
        gl_lds16(W + (size_t)(n0 + r0) * ldw + (kk) + k0, &Bs[buf][tid * 8]); }

    STG(0, 0);
    __syncthreads();

    for (int t = 0; t < NT; ++t) {
        const int b = t & 1;
        if (t + 1 < NT) STG(b ^ 1, (t + 1) << 5);

        bf16x8 af[4], bw[2];
        #pragma unroll
        for (int m = 0; m < 4; ++m)
            af[m] = *(const bf16x8*)&As[b][(wr + m * 16 + frow) * 32 + fk];
        #pragma unroll
        for (int n = 0; n < 2; ++n)
            bw[n] = *(const bf16x8*)&Bs[b][(wc + n * 16 + frow) * 32 + fk];

        #pragma unroll
        for (int m = 0; m < 4; ++m)
            #pragma unroll
            for (int n = 0; n < 2; ++n)
                acc[m][n] = __builtin_amdgcn_mfma_f32_16x16x32_bf16(
                    af[m], bw[n], acc[m][n], 0, 0, 0);

        __syncthreads();
    }
#undef STG

    const int crow = (lane >> 4) * 4;
    const int ccol = lane & 15;
    #pragma unroll
    for (int m = 0; m < 4; ++m)
        #pragma unroll
        for (int n = 0; n < 2; ++n)
            #pragma unroll
            for (int r = 0; r < 4; ++r)
                C[(size_t)(m0 + wr + m * 16 + crow + r) * N
                  + n0 + wc + n * 16 + ccol] = acc[m][n][r];
}

// ---------------------------------------------------------------------------
// Early pack: u->ubf, Wip->Wipb, Wop->wopb (bf16), [xdt;xb;xc]^T->Wt (fp32),
// Aneg = -exp(A_log)
// ---------------------------------------------------------------------------
#define NU4  (L * DM / 4)            // 786432
#define NW4  (2 * DI * DM / 4)       // 589824
#define NO4  (DM * DI / 4)           // 294912
#define NWT  (DI * NCOMB)            // 122880
#define NA   (DI * DS)               // 24576
__global__ __launch_bounds__(256)
void pack_early_k(const float* __restrict__ u, const float* __restrict__ Wip,
                  const float* __restrict__ Wop,
                  const float* __restrict__ xdt, const float* __restrict__ xb,
                  const float* __restrict__ xc, const float* __restrict__ alog,
                  u16* __restrict__ ubf, u16* __restrict__ Wipb,
                  u16* __restrict__ wopb,
                  float* __restrict__ Wt, float* __restrict__ Aneg)
{
    int i = blockIdx.x * 256 + threadIdx.x;
    if (i < NU4) {
        const float4 v = ((const float4*)u)[i];
        ushort4 o; o.x = f2bf(v.x); o.y = f2bf(v.y); o.z = f2bf(v.z); o.w = f2bf(v.w);
        ((ushort4*)ubf)[i] = o;
        return;
    }
    i -= NU4;
    if (i < NW4) {
        const float4 v = ((const float4*)Wip)[i];
        ushort4 o; o.x = f2bf(v.x); o.y = f2bf(v.y); o.z = f2bf(v.z); o.w = f2bf(v.w);
        ((ushort4*)Wipb)[i] = o;
        return;
    }
    i -= NW4;
    if (i < NO4) {
        const float4 v = ((const float4*)Wop)[i];
        ushort4 o; o.x = f2bf(v.x); o.y = f2bf(v.y); o.z = f2bf(v.z); o.w = f2bf(v.w);
        ((ushort4*)wopb)[i] = o;
        return;
    }
    i -= NO4;
    if (i < NWT) {
        const int k = i / NCOMB, n = i - k * NCOMB;
        float v;
        if (n < 48)      v = xdt[n * DI + k];
        else if (n < 64) v = xb[(n - 48) * DI + k];
        else             v = xc[(n - 64) * DI + k];
        Wt[i] = v;
        return;
    }
    i -= NWT;
    if (i < NA)
        Aneg[i] = -expf(alog[i]);
}

// ---------------------------------------------------------------------------
// Causal depthwise conv (width 4) + bias + SiLU. bf16 in (xzb x-half),
// bf16 out (xcvb). 4 channels/thread.
// ---------------------------------------------------------------------------
__global__ __launch_bounds__(256)
void conv_silu_v4(const u16* __restrict__ xzb, const float* __restrict__ cw,
                  const float* __restrict__ cb, u16* __restrict__ xcvb)
{
    int idx = blockIdx.x * 256 + threadIdx.x;
    if (idx >= L * (DI / 4)) return;
    const int t = idx / (DI / 4);
    const int q = idx - t * (DI / 4);
    const int d = q * 4;

    const float4 w0 = ((const float4*)cw)[d + 0];
    const float4 w1 = ((const float4*)cw)[d + 1];
    const float4 w2 = ((const float4*)cw)[d + 2];
    const float4 w3 = ((const float4*)cw)[d + 3];
    float4 acc = ((const float4*)cb)[q];

    const u16* base = xzb + d;
    #pragma unroll
    for (int j = 0; j < 4; ++j) {
        const int tt = t - 3 + j;
        if (tt >= 0) {
            const ushort4 xb4 = *(const ushort4*)(base + (size_t)tt * XZROW);
            acc.x = fmaf(((const float*)&w0)[j], bf2f(xb4.x), acc.x);
            acc.y = fmaf(((const float*)&w1)[j], bf2f(xb4.y), acc.y);
            acc.z = fmaf(((const float*)&w2)[j], bf2f(xb4.z), acc.z);
            acc.w = fmaf(((const float*)&w3)[j], bf2f(xb4.w), acc.w);
        }
    }
    ushort4 o;
    o.x = f2bf(silu_f(acc.x)); o.y = f2bf(silu_f(acc.y));
    o.z = f2bf(silu_f(acc.z)); o.w = f2bf(silu_f(acc.w));
    ((ushort4*)xcvb)[idx] = o;
}

// ---------------------------------------------------------------------------
// GEMM2 split-K: part[s][L][80] = xcvb[L][DI-slice] @ Wt[DI-slice][80]
// A is bf16 now; converted during LDS staging.
// ---------------------------------------------------------------------------
__global__ __launch_bounds__(256)
void gemm2_splitk(const u16* __restrict__ A, const float* __restrict__ Wt,
                  float* __restrict__ part)
{
    __shared__ float As[G2_KC][65];     // +1 pad
    __shared__ float Ws[G2_KC][80];

    const int tid  = threadIdx.x;
    const int m0   = blockIdx.x * 64;
    const int koff = blockIdx.y * G2_KC;

    {
        const int r = tid >> 2, cg = tid & 3;
        #pragma unroll
        for (int j = 0; j < 6; ++j) {
            const int kk = (j * 4 + cg) * 4;
            const ushort4 v = *(const ushort4*)(A + (size_t)(m0 + r) * DI + koff + kk);
            As[kk + 0][r] = bf2f(v.x); As[kk + 1][r] = bf2f(v.y);
            As[kk + 2][r] = bf2f(v.z); As[kk + 3][r] = bf2f(v.w);
        }
    }
    for (int i = tid; i < G2_KC * 80; i += 256)
        (&Ws[0][0])[i] = Wt[(size_t)koff * 80 + i];
    __syncthreads();

    const int g  = tid >> 6;
    const int r  = tid & 63;
    const int c0 = g * 20;

    float acc[20];
    #pragma unroll
    for (int j = 0; j < 20; ++j) acc[j] = 0.f;

    #pragma unroll 2
    for (int k = 0; k < G2_KC; ++k) {
        const float a = As[k][r];
        #pragma unroll
        for (int q = 0; q < 5; ++q) {
            const float4 w = *(const float4*)&Ws[k][c0 + q * 4];
            acc[q * 4 + 0] = fmaf(a, w.x, acc[q * 4 + 0]);
            acc[q * 4 + 1] = fmaf(a, w.y, acc[q * 4 + 1]);
            acc[q * 4 + 2] = fmaf(a, w.z, acc[q * 4 + 2]);
            acc[q * 4 + 3] = fmaf(a, w.w, acc[q * 4 + 3]);
        }
    }

    float* p = part + (size_t)blockIdx.y * (L * NCOMB)
                    + (size_t)(m0 + r) * NCOMB + c0;
    #pragma unroll
    for (int q = 0; q < 5; ++q)
        ((float4*)p)[q] = make_float4(acc[q * 4], acc[q * 4 + 1],
                                      acc[q * 4 + 2], acc[q * 4 + 3]);
}

__global__ __launch_bounds__(256)
void gemm2_reduce(const float* __restrict__ part, float* __restrict__ dtbc)
{
    int i = blockIdx.x * 256 + threadIdx.x;
    if (i >= L * NCOMB) return;
    float s = 0.f;
    #pragma unroll
    for (int j = 0; j < G2_S; ++j)
        s += part[(size_t)j * L * NCOMB + i];
    dtbc[i] = s;
}

// ---------------------------------------------------------------------------
// dt = softplus(dtr @ dtw^T + dtb), stored bf16. Block = 256 ch x 32 t.
// ---------------------------------------------------------------------------
__global__ __launch_bounds__(256)
void dt_k(const float* __restrict__ dtbc, const float* __restrict__ dtw,
          const float* __restrict__ dtb, u16* __restrict__ dt)
{
    __shared__ float dtr_s[32][48];
    const int tid = threadIdx.x;
    const int d   = blockIdx.x * 256 + tid;
    const int t0  = blockIdx.y * 32;

    for (int i = tid; i < 384; i += 256) {
        const int r = i / 12, c = (i - r * 12) * 4;
        const float4 v = *(const float4*)(dtbc + (size_t)(t0 + r) * NCOMB + c);
        *(float4*)&dtr_s[r][c] = v;
    }
    __syncthreads();

    float w[48];
    #pragma unroll
    for (int j = 0; j < 12; ++j) {
        const float4 v = *(const float4*)(dtw + (size_t)d * DR + j * 4);
        w[j * 4 + 0] = v.x; w[j * 4 + 1] = v.y;
        w[j * 4 + 2] = v.z; w[j * 4 + 3] = v.w;
    }
    const float b = dtb[d];

    for (int t = 0; t < 32; ++t) {
        float s = b;
        #pragma unroll
        for (int j = 0; j < 12; ++j) {
            const float4 v = *(const float4*)&dtr_s[t][j * 4];
            s = fmaf(v.x, w[j * 4 + 0], s);
            s = fmaf(v.y, w[j * 4 + 1], s);
            s = fmaf(v.z, w[j * 4 + 2], s);
            s = fmaf(v.w, w[j * 4 + 3], s);
        }
        dt[(size_t)(t0 + t) * DI + d] = f2bf(softplus_f(s));
    }
}

// ---------------------------------------------------------------------------
// Scan pass 1: per-chunk local states (bf16) + dt chunk-sums. CH=32.
// dt and xcv are both bf16 now.
// ---------------------------------------------------------------------------
__global__ __launch_bounds__(256)
void scan1_k(const u16* __restrict__ dt, const u16* __restrict__ xcv,
             const float* __restrict__ dtbc, const float* __restrict__ Aneg,
             u16* __restrict__ hloc, float* __restrict__ Ssum)
{
    __shared__ float Bs[CH][DS];
    const int c = blockIdx.y;
    const int d = blockIdx.x * 256 + threadIdx.x;

    for (int i = threadIdx.x; i < CH * DS; i += 256) {
        int tt = i >> 4, n = i & 15;
        Bs[tt][n] = dtbc[(size_t)(c * CH + tt) * NCOMB + 48 + n];
    }
    __syncthreads();

    float Ad[DS], h[DS];
    #pragma unroll
    for (int q = 0; q < 4; ++q)
        *(float4*)&Ad[q * 4] = *(const float4*)(Aneg + (size_t)d * DS + q * 4);
    #pragma unroll
    for (int n = 0; n < DS; ++n) h[n] = 0.f;

    size_t base = (size_t)(c * CH) * DI + d;
    float S = 0.f;
    for (int tt = 0; tt < CH; ++tt, base += DI) {
        const float dtv = bf2f(dt[base]);
        const float xv  = bf2f(xcv[base]);
        S += dtv;
        const float xdt = xv * dtv;
        #pragma unroll
        for (int n = 0; n < DS; ++n)
            h[n] = fmaf(h[n], __expf(Ad[n] * dtv), xdt * Bs[tt][n]);
    }

    u16* o = hloc + ((size_t)c * DI + d) * DS;
    #pragma unroll
    for (int q = 0; q < 4; ++q) {
        ushort4 pk;
        pk.x = f2bf(h[q * 4 + 0]); pk.y = f2bf(h[q * 4 + 1]);
        pk.z = f2bf(h[q * 4 + 2]); pk.w = f2bf(h[q * 4 + 3]);
        *(ushort4*)(o + q * 4) = pk;
    }
    Ssum[c * DI + d] = S;
}

// ---------------------------------------------------------------------------
// Scan pass 2: scan the NC chunk carries per (d,n); hc bf16 in-place.
// ---------------------------------------------------------------------------
__global__ __launch_bounds__(256)
void scan2_k(u16* hc, const float* __restrict__ Ssum,
             const float* __restrict__ Aneg)
{
    const int p = blockIdx.x * 256 + threadIdx.x;
    if (p >= DI * DS) return;
    const int d = p >> 4;
    const float Ad = Aneg[p];
    float h = 0.f;
    for (int c = 0; c < NC; ++c) {
        const size_t o = (size_t)c * DI * DS + p;
        const float hl = bf2f(hc[o]);     // local state
        hc[o] = f2bf(h);                  // overwrite with carry-in
        h = fmaf(h, __expf(Ad * Ssum[c * DI + d]), hl);
    }
}

// ---------------------------------------------------------------------------
// Scan pass 3: replay with carry-in; emit yz bf16 into dead x-half of xzb.
// z read from bf16 z-half of xzb.
// ---------------------------------------------------------------------------
__global__ __launch_bounds__(256)
void scan3_k(const u16* __restrict__ dt, const u16* __restrict__ xcv,
             const float* __restrict__ dtbc, const float* __restrict__ Aneg,
             const u16* __restrict__ carry, const float* __restrict__ Dp,
             const u16* __restrict__ xzb, u16* __restrict__ ybf)
{
    __shared__ float Bs[CH][DS];
    __shared__ float Cs[CH][DS];
    const int c = blockIdx.y;
    const int d = blockIdx.x * 256 + threadIdx.x;

    for (int i = threadIdx.x; i < CH * DS; i += 256) {
        int tt = i >> 4, n = i & 15;
        Bs[tt][n] = dtbc[(size_t)(c * CH + tt) * NCOMB + 48 + n];
        Cs[tt][n] = dtbc[(size_t)(c * CH + tt) * NCOMB + 64 + n];
    }
    __syncthreads();

    float Ad[DS], h[DS];
    const u16* co = carry + ((size_t)c * DI + d) * DS;
    #pragma unroll
    for (int q = 0; q < 4; ++q) {
        const ushort4 cv = *(const ushort4*)(co + q * 4);
        h[q * 4 + 0] = bf2f(cv.x); h[q * 4 + 1] = bf2f(cv.y);
        h[q * 4 + 2] = bf2f(cv.z); h[q * 4 + 3] = bf2f(cv.w);
    }
    #pragma unroll
    for (int q = 0; q < 4; ++q)
        *(float4*)&Ad[q * 4] = *(const float4*)(Aneg + (size_t)d * DS + q * 4);
    const float Dv = Dp[d];

    int t = c * CH;
    for (int tt = 0; tt < CH; ++tt, ++t) {
        const size_t o = (size_t)t * DI + d;
        const float dtv = bf2f(dt[o]);
        const float xv  = bf2f(xcv[o]);
        const float xdt = xv * dtv;
        float y = Dv * xv;
        #pragma unroll
        for (int n = 0; n < DS; ++n) {
            h[n] = fmaf(h[n], __expf(Ad[n] * dtv), xdt * Bs[tt][n]);
            y = fmaf(h[n], Cs[tt][n], y);
        }
        const float z = bf2f(xzb[(size_t)t * XZROW + DI + d]);
        ybf[(size_t)t * XZROW + d] = f2bf(y * silu_f(z));
    }
}

// ---------------------------------------------------------------------------
extern "C" void kernel_launch(void* const* d_in, const int* in_sizes, int n_in,
                              void* d_out, int out_size, void* d_ws, size_t ws_size,
                              hipStream_t stream)
{
    const float* u    = (const float*)d_in[0];
    const float* Wip  = (const float*)d_in[1];
    const float* cw   = (const float*)d_in[2];
    const float* cb   = (const float*)d_in[3];
    const float* xdt  = (const float*)d_in[4];
    const float* xbw  = (const float*)d_in[5];
    const float* xcw  = (const float*)d_in[6];
    const float* dtw  = (const float*)d_in[7];
    const float* dtb  = (const float*)d_in[8];
    const float* alog = (const float*)d_in[9];
    const float* Dp   = (const float*)d_in[10];
    const float* Wop  = (const float*)d_in[11];
    float* out = (float*)d_out;

    // workspace layout (float units) — ~75 MB
    float* ws   = (float*)d_ws;
    u16*   xzb  = (u16*)ws;                          // [4096][3072] bf16 -> 6.29M fl
    u16*   xcvb = (u16*)(ws + (size_t)L * XZROW / 2);// [4096][1536] bf16 -> 3.15M fl
    float* dtbc = ws + (size_t)L * XZROW / 2
                     + (size_t)L * DI / 2;           // L*NCOMB fp32
    float* dty  = dtbc + (size_t)L * NCOMB;          // L*DI region (g2p, then dt bf16)
    float* Wt   = dty  + (size_t)L * DI;             // DI*NCOMB
    u16*   hc   = (u16*)(Wt + (size_t)DI * NCOMB);   // NC*DI*DS u16
    float* Ssum = Wt + (size_t)DI * NCOMB
                     + (size_t)NC * DI * DS / 2;     // NC*DI
    float* Aneg = Ssum + (size_t)NC * DI;            // DI*DS
    u16*   wopb = (u16*)(Aneg + NA);                 // [768][1536] bf16

    // aliases into regions dead at time of use
    u16*   ubf  = xcvb;                        // [4096][768]  (dead until conv)
    u16*   Wipb = xcvb + (size_t)L * DM;       // [3072][768]  (dead until conv)
    float* g2p  = dty;                         // [16][4096][80] (dead after reduce)
    u16*   dtbf = (u16*)dty;                   // [4096][1536] bf16 dt (after reduce)
    u16*   ybf  = xzb;                         // x-half of xzb rows (dead after conv)

    const dim3 blk(256);

    // 1) early packs: ubf, Wipb, wopb (bf16), Wt, Aneg
    pack_early_k<<<(NU4 + NW4 + NO4 + NWT + NA + 255) / 256, blk, 0, stream>>>(
        u, Wip, Wop, xdt, xbw, xcw, alog, ubf, Wipb, wopb, Wt, Aneg);

    // 2) xz = u @ in_proj_w^T   [4096, 3072] bf16 out (bf16 MFMA, K=768)
    gemm_bf16_bt_o16<<<dim3((2 * DI) / 128, L / 128), blk, 0, stream>>>(
        ubf, Wipb, xzb, L, 2 * DI, DM);

    // 3) causal conv + SiLU -> xcvb (bf16 in/out)
    conv_silu_v4<<<(L * (DI / 4) + 255) / 256, blk, 0, stream>>>(xzb, cw, cb, xcvb);

    // 4) [dt_rank|B|C] = xcvb @ Wt via split-K (partials in dty region)
    gemm2_splitk<<<dim3(L / 64, G2_S), blk, 0, stream>>>(xcvb, Wt, g2p);
    gemm2_reduce<<<(L * NCOMB + 255) / 256, blk, 0, stream>>>(g2p, dtbc);

    // 5) dt = softplus(dtr @ dtw^T + dtb) -> bf16 (overwrites g2p region)
    dt_k<<<dim3(DI / 256, L / 32), blk, 0, stream>>>(dtbc, dtw, dtb, dtbf);

    // 6-8) chunked selective scan (CH=32, 128 chunks)
    scan1_k<<<dim3(DI / 256, NC), blk, 0, stream>>>(
        dtbf, xcvb, dtbc, Aneg, hc, Ssum);
    scan2_k<<<(DI * DS) / 256, blk, 0, stream>>>(hc, Ssum, Aneg);
    scan3_k<<<dim3(DI / 256, NC), blk, 0, stream>>>(
        dtbf, xcvb, dtbc, Aneg, hc, Dp, xzb, ybf);

    // 9) out = yz @ out_proj_w^T   [4096, 768]  (bf16 MFMA; A strided in xzb)
    gemm_bf16_bt_n64<<<dim3(DM / 64, L / 128), blk, 0, stream>>>(
        ybf, XZROW, wopb, DI, out, L, DM, DI);
}

// Round 13
// 223.645 us; speedup vs baseline: 2.5355x; 1.0325x over previous
//
#include <hip/hip_runtime.h>
#include <math.h>

// Problem constants (UnifiedMambaBlock, B=1)
#define L      4096
#define DM     768
#define DI     1536
#define DS     16
#define DR     48
#define NCOMB  80     // 48 dt_rank + 16 B + 16 C
#define CH     32     // scan chunk length
#define NC     128    // number of chunks (L / CH)
#define G2_S   16     // GEMM2 K-splits
#define G2_KC  96     // 1536 / 16
#define XZROW  3072   // xz row stride in u16 (bf16 [4096][3072])

typedef unsigned short u16;
typedef unsigned int   u32;
typedef __attribute__((ext_vector_type(8))) short bf16x8;   // 8 bf16 = 4 VGPRs
typedef __attribute__((ext_vector_type(8))) unsigned short u16x8;
typedef __attribute__((ext_vector_type(4))) float f32x4;

__device__ __forceinline__ float silu_f(float v) { return v / (1.f + __expf(-v)); }

__device__ __forceinline__ u16 f2bf(float f) {              // RNE f32 -> bf16
    u32 u = __float_as_uint(f);
    return (u16)((u + 0x7fffu + ((u >> 16) & 1u)) >> 16);
}
__device__ __forceinline__ float bf2f(u16 h) {
    return __uint_as_float(((u32)h) << 16);
}

__device__ __forceinline__ float softplus_f(float s) {
    return (s > 20.f) ? s : log1pf(expf(s));
}

__device__ __forceinline__ void gl_lds16(const u16* g, u16* l) {
    __builtin_amdgcn_global_load_lds(
        (const __attribute__((address_space(1))) void*)g,
        (__attribute__((address_space(3))) void*)l, 16, 0, 0);
}

// Power tree: given e1 = exp(a), fill e[n] = e1^(n+1), n=0..15 (depth-4 muls)
#define POWTREE(e, e1) {                                                       \
    e[0] = (e1);                                                               \
    e[1] = e[0]*e[0];  e[2] = e[1]*e[0];  e[3] = e[1]*e[1];                    \
    e[4] = e[3]*e[0];  e[5] = e[2]*e[2];  e[6] = e[3]*e[2];  e[7] = e[3]*e[3]; \
    e[8] = e[7]*e[0];  e[9] = e[7]*e[1];  e[10]= e[7]*e[2];  e[11]= e[7]*e[3]; \
    e[12]= e[7]*e[4];  e[13]= e[7]*e[5];  e[14]= e[7]*e[6];  e[15]= e[7]*e[7]; }

// ---------------------------------------------------------------------------
// bf16 MFMA GEMM (m97 structure), BF16 OUTPUT: Cb[M][N] bf16 = A @ W^T.
// ---------------------------------------------------------------------------
__global__ __launch_bounds__(256)
void gemm_bf16_bt_o16(const u16* __restrict__ A, const u16* __restrict__ W,
                      u16* __restrict__ Cb, int M, int N, int K)
{
    __shared__ u16 As[2][128 * 32];
    __shared__ u16 Bs[2][128 * 32];

    const int tid  = threadIdx.x;
    const int lane = tid & 63;
    const int wave = tid >> 6;
    const int wr   = (wave >> 1) * 64;
    const int wc   = (wave & 1) * 64;
    const int m0   = blockIdx.y * 128;
    const int n0   = blockIdx.x * 128;

    const int r0 = tid >> 2;
    const int k0 = (tid & 3) * 8;

    const int frow = lane & 15;
    const int fk   = (lane >> 4) * 8;

    f32x4 acc[4][4];
    #pragma unroll
    for (int i = 0; i < 4; ++i)
        #pragma unroll
        for (int j = 0; j < 4; ++j)
            acc[i][j] = (f32x4){0.f, 0.f, 0.f, 0.f};

    const int NT = K >> 5;

#define STAGE(buf, kk) {                                                       \
        const u16* ga = A + (size_t)(m0 + r0) * K + (kk) + k0;                 \
        const u16* gw = W + (size_t)(n0 + r0) * K + (kk) + k0;                 \
        gl_lds16(ga,                   &As[buf][tid * 8]);                     \
        gl_lds16(ga + (size_t)64 * K,  &As[buf][2048 + tid * 8]);              \
        gl_lds16(gw,                   &Bs[buf][tid * 8]);                     \
        gl_lds16(gw + (size_t)64 * K,  &Bs[buf][2048 + tid * 8]); }

    STAGE(0, 0);
    __syncthreads();

    for (int t = 0; t < NT; ++t) {
        const int b = t & 1;
        if (t + 1 < NT) STAGE(b ^ 1, (t + 1) << 5);

        bf16x8 af[4], bw[4];
        #pragma unroll
        for (int m = 0; m < 4; ++m)
            af[m] = *(const bf16x8*)&As[b][(wr + m * 16 + frow) * 32 + fk];
        #pragma unroll
        for (int n = 0; n < 4; ++n)
            bw[n] = *(const bf16x8*)&Bs[b][(wc + n * 16 + frow) * 32 + fk];

        #pragma unroll
        for (int m = 0; m < 4; ++m)
            #pragma unroll
            for (int n = 0; n < 4; ++n)
                acc[m][n] = __builtin_amdgcn_mfma_f32_16x16x32_bf16(
                    af[m], bw[n], acc[m][n], 0, 0, 0);

        __syncthreads();
    }
#undef STAGE

    const int crow = (lane >> 4) * 4;
    const int ccol = lane & 15;
    #pragma unroll
    for (int m = 0; m < 4; ++m)
        #pragma unroll
        for (int n = 0; n < 4; ++n)
            #pragma unroll
            for (int r = 0; r < 4; ++r)
                Cb[(size_t)(m0 + wr + m * 16 + crow + r) * N
                   + n0 + wc + n * 16 + ccol] = f2bf(acc[m][n][r]);
}

// ---------------------------------------------------------------------------
// bf16 MFMA GEMM with strided rows (lda/ldw in u16 elems), 128(M)x64(N) tile,
// fp32 output. Used for GEMM4.
// ---------------------------------------------------------------------------
__global__ __launch_bounds__(256)
void gemm_bf16_bt_n64(const u16* __restrict__ A, int lda,
                      const u16* __restrict__ W, int ldw,
                      float* __restrict__ C, int M, int N, int K)
{
    __shared__ u16 As[2][128 * 32];
    __shared__ u16 Bs[2][64 * 32];

    const int tid  = threadIdx.x;
    const int lane = tid & 63;
    const int wave = tid >> 6;
    const int wr   = (wave >> 1) * 64;
    const int wc   = (wave & 1) * 32;
    const int m0   = blockIdx.y * 128;
    const int n0   = blockIdx.x * 64;

    const int r0 = tid >> 2;
    const int k0 = (tid & 3) * 8;

    const int frow = lane & 15;
    const int fk   = (lane >> 4) * 8;

    f32x4 acc[4][2];
    #pragma unroll
    for (int i = 0; i < 4; ++i)
        #pragma unroll
        for (int j = 0; j < 2; ++j)
            acc[i][j] = (f32x4){0.f, 0.f, 0.f, 0.f};

    const int NT = K >> 5;

#define STG(buf, kk) {                                                         \
        const u16* ga = A + (size_t)(m0 + r0) * lda + (kk) + k0;               \
        gl_lds16(ga,                     &As[buf][tid * 8]);                   \
        gl_lds16(ga + (size_t)64 * lda,  &As[buf][2048 + tid * 8]);            \
        gl_lds16(W + (size_t)(n0 + r0) * ldw + (kk) + k0, &Bs[buf][tid * 8]); }

    STG(0, 0);
    __syncthreads();

    for (int t = 0; t < NT; ++t) {
        const int b = t & 1;
        if (t + 1 < NT) STG(b ^ 1, (t + 1) << 5);

        bf16x8 af[4], bw[2];
        #pragma unroll
        for (int m = 0; m < 4; ++m)
            af[m] = *(const bf16x8*)&As[b][(wr + m * 16 + frow) * 32 + fk];
        #pragma unroll
        for (int n = 0; n < 2; ++n)
            bw[n] = *(const bf16x8*)&Bs[b][(wc + n * 16 + frow) * 32 + fk];

        #pragma unroll
        for (int m = 0; m < 4; ++m)
            #pragma unroll
            for (int n = 0; n < 2; ++n)
                acc[m][n] = __builtin_amdgcn_mfma_f32_16x16x32_bf16(
                    af[m], bw[n], acc[m][n], 0, 0, 0);

        __syncthreads();
    }
#undef STG

    const int crow = (lane >> 4) * 4;
    const int ccol = lane & 15;
    #pragma unroll
    for (int m = 0; m < 4; ++m)
        #pragma unroll
        for (int n = 0; n < 2; ++n)
            #pragma unroll
            for (int r = 0; r < 4; ++r)
                C[(size_t)(m0 + wr + m * 16 + crow + r) * N
                  + n0 + wc + n * 16 + ccol] = acc[m][n][r];
}

// ---------------------------------------------------------------------------
// Early pack: u->ubf, Wip->Wipb, Wop->wopb (bf16), [xdt;xb;xc]^T->Wt (fp32),
// Aneg = -exp(A_log)
// ---------------------------------------------------------------------------
#define NU4  (L * DM / 4)            // 786432
#define NW4  (2 * DI * DM / 4)       // 589824
#define NO4  (DM * DI / 4)           // 294912
#define NWT  (DI * NCOMB)            // 122880
#define NA   (DI * DS)               // 24576
__global__ __launch_bounds__(256)
void pack_early_k(const float* __restrict__ u, const float* __restrict__ Wip,
                  const float* __restrict__ Wop,
                  const float* __restrict__ xdt, const float* __restrict__ xb,
                  const float* __restrict__ xc, const float* __restrict__ alog,
                  u16* __restrict__ ubf, u16* __restrict__ Wipb,
                  u16* __restrict__ wopb,
                  float* __restrict__ Wt, float* __restrict__ Aneg)
{
    int i = blockIdx.x * 256 + threadIdx.x;
    if (i < NU4) {
        const float4 v = ((const float4*)u)[i];
        ushort4 o; o.x = f2bf(v.x); o.y = f2bf(v.y); o.z = f2bf(v.z); o.w = f2bf(v.w);
        ((ushort4*)ubf)[i] = o;
        return;
    }
    i -= NU4;
    if (i < NW4) {
        const float4 v = ((const float4*)Wip)[i];
        ushort4 o; o.x = f2bf(v.x); o.y = f2bf(v.y); o.z = f2bf(v.z); o.w = f2bf(v.w);
        ((ushort4*)Wipb)[i] = o;
        return;
    }
    i -= NW4;
    if (i < NO4) {
        const float4 v = ((const float4*)Wop)[i];
        ushort4 o; o.x = f2bf(v.x); o.y = f2bf(v.y); o.z = f2bf(v.z); o.w = f2bf(v.w);
        ((ushort4*)wopb)[i] = o;
        return;
    }
    i -= NO4;
    if (i < NWT) {
        const int k = i / NCOMB, n = i - k * NCOMB;
        float v;
        if (n < 48)      v = xdt[n * DI + k];
        else if (n < 64) v = xb[(n - 48) * DI + k];
        else             v = xc[(n - 64) * DI + k];
        Wt[i] = v;
        return;
    }
    i -= NWT;
    if (i < NA)
        Aneg[i] = -expf(alog[i]);
}

// ---------------------------------------------------------------------------
// Causal depthwise conv (width 4) + bias + SiLU. bf16 in/out, 8 ch/thread.
// ---------------------------------------------------------------------------
__global__ __launch_bounds__(256)
void conv_silu_v8(const u16* __restrict__ xzb, const float* __restrict__ cw,
                  const float* __restrict__ cb, u16* __restrict__ xcvb)
{
    int idx = blockIdx.x * 256 + threadIdx.x;
    if (idx >= L * (DI / 8)) return;
    const int t = idx / (DI / 8);
    const int q = idx - t * (DI / 8);
    const int d = q * 8;

    float w[8][4];
    #pragma unroll
    for (int j = 0; j < 8; ++j)
        *(float4*)w[j] = ((const float4*)cw)[d + j];

    float acc[8];
    {
        const float4 b0 = ((const float4*)cb)[q * 2];
        const float4 b1 = ((const float4*)cb)[q * 2 + 1];
        acc[0] = b0.x; acc[1] = b0.y; acc[2] = b0.z; acc[3] = b0.w;
        acc[4] = b1.x; acc[5] = b1.y; acc[6] = b1.z; acc[7] = b1.w;
    }

    const u16* base = xzb + d;
    #pragma unroll
    for (int j = 0; j < 4; ++j) {
        const int tt = t - 3 + j;
        if (tt >= 0) {
            const u16x8 x8 = *(const u16x8*)(base + (size_t)tt * XZROW);
            #pragma unroll
            for (int k = 0; k < 8; ++k)
                acc[k] = fmaf(w[k][j], bf2f(x8[k]), acc[k]);
        }
    }
    u16x8 o;
    #pragma unroll
    for (int k = 0; k < 8; ++k)
        o[k] = f2bf(silu_f(acc[k]));
    ((u16x8*)xcvb)[idx] = o;
}

// ---------------------------------------------------------------------------
// GEMM2 split-K: part[s][L][80] = xcvb[L][DI-slice] @ Wt[DI-slice][80]
// ---------------------------------------------------------------------------
__global__ __launch_bounds__(256)
void gemm2_splitk(const u16* __restrict__ A, const float* __restrict__ Wt,
                  float* __restrict__ part)
{
    __shared__ float As[G2_KC][65];     // +1 pad
    __shared__ float Ws[G2_KC][80];

    const int tid  = threadIdx.x;
    const int m0   = blockIdx.x * 64;
    const int koff = blockIdx.y * G2_KC;

    {
        const int r = tid >> 2, cg = tid & 3;
        #pragma unroll
        for (int j = 0; j < 6; ++j) {
            const int kk = (j * 4 + cg) * 4;
            const ushort4 v = *(const ushort4*)(A + (size_t)(m0 + r) * DI + koff + kk);
            As[kk + 0][r] = bf2f(v.x); As[kk + 1][r] = bf2f(v.y);
            As[kk + 2][r] = bf2f(v.z); As[kk + 3][r] = bf2f(v.w);
        }
    }
    for (int i = tid; i < G2_KC * 80; i += 256)
        (&Ws[0][0])[i] = Wt[(size_t)koff * 80 + i];
    __syncthreads();

    const int g  = tid >> 6;
    const int r  = tid & 63;
    const int c0 = g * 20;

    float acc[20];
    #pragma unroll
    for (int j = 0; j < 20; ++j) acc[j] = 0.f;

    #pragma unroll 2
    for (int k = 0; k < G2_KC; ++k) {
        const float a = As[k][r];
        #pragma unroll
        for (int q = 0; q < 5; ++q) {
            const float4 w = *(const float4*)&Ws[k][c0 + q * 4];
            acc[q * 4 + 0] = fmaf(a, w.x, acc[q * 4 + 0]);
            acc[q * 4 + 1] = fmaf(a, w.y, acc[q * 4 + 1]);
            acc[q * 4 + 2] = fmaf(a, w.z, acc[q * 4 + 2]);
            acc[q * 4 + 3] = fmaf(a, w.w, acc[q * 4 + 3]);
        }
    }

    float* p = part + (size_t)blockIdx.y * (L * NCOMB)
                    + (size_t)(m0 + r) * NCOMB + c0;
    #pragma unroll
    for (int q = 0; q < 5; ++q)
        ((float4*)p)[q] = make_float4(acc[q * 4], acc[q * 4 + 1],
                                      acc[q * 4 + 2], acc[q * 4 + 3]);
}

__global__ __launch_bounds__(256)
void gemm2_reduce(const float* __restrict__ part, float* __restrict__ dtbc)
{
    int i = blockIdx.x * 256 + threadIdx.x;
    if (i >= L * NCOMB) return;
    float s = 0.f;
    #pragma unroll
    for (int j = 0; j < G2_S; ++j)
        s += part[(size_t)j * L * NCOMB + i];
    dtbc[i] = s;
}

// ---------------------------------------------------------------------------
// dt = softplus(dtr @ dtw^T + dtb), stored bf16. Block = 256 ch x 32 t.
// ---------------------------------------------------------------------------
__global__ __launch_bounds__(256)
void dt_k(const float* __restrict__ dtbc, const float* __restrict__ dtw,
          const float* __restrict__ dtb, u16* __restrict__ dt)
{
    __shared__ float dtr_s[32][48];
    const int tid = threadIdx.x;
    const int d   = blockIdx.x * 256 + tid;
    const int t0  = blockIdx.y * 32;

    for (int i = tid; i < 384; i += 256) {
        const int r = i / 12, c = (i - r * 12) * 4;
        const float4 v = *(const float4*)(dtbc + (size_t)(t0 + r) * NCOMB + c);
        *(float4*)&dtr_s[r][c] = v;
    }
    __syncthreads();

    float w[48];
    #pragma unroll
    for (int j = 0; j < 12; ++j) {
        const float4 v = *(const float4*)(dtw + (size_t)d * DR + j * 4);
        w[j * 4 + 0] = v.x; w[j * 4 + 1] = v.y;
        w[j * 4 + 2] = v.z; w[j * 4 + 3] = v.w;
    }
    const float b = dtb[d];

    for (int t = 0; t < 32; ++t) {
        float s = b;
        #pragma unroll
        for (int j = 0; j < 12; ++j) {
            const float4 v = *(const float4*)&dtr_s[t][j * 4];
            s = fmaf(v.x, w[j * 4 + 0], s);
            s = fmaf(v.y, w[j * 4 + 1], s);
            s = fmaf(v.z, w[j * 4 + 2], s);
            s = fmaf(v.w, w[j * 4 + 3], s);
        }
        dt[(size_t)(t0 + t) * DI + d] = f2bf(softplus_f(s));
    }
}

// ---------------------------------------------------------------------------
// Scan pass 1: per-chunk local states (bf16) + dt chunk-sums. CH=32.
// Fast path: Ad[n] = (n+1)*Ad[0] (verified per-thread) -> 1 exp + power tree.
// ---------------------------------------------------------------------------
__global__ __launch_bounds__(256)
void scan1_k(const u16* __restrict__ dt, const u16* __restrict__ xcv,
             const float* __restrict__ dtbc, const float* __restrict__ Aneg,
             u16* __restrict__ hloc, float* __restrict__ Ssum)
{
    __shared__ float Bs[CH][DS];
    const int c = blockIdx.y;
    const int d = blockIdx.x * 256 + threadIdx.x;

    for (int i = threadIdx.x; i < CH * DS; i += 256) {
        int tt = i >> 4, n = i & 15;
        Bs[tt][n] = dtbc[(size_t)(c * CH + tt) * NCOMB + 48 + n];
    }
    __syncthreads();

    float Ad[DS], h[DS];
    #pragma unroll
    for (int q = 0; q < 4; ++q)
        *(float4*)&Ad[q * 4] = *(const float4*)(Aneg + (size_t)d * DS + q * 4);
    #pragma unroll
    for (int n = 0; n < DS; ++n) h[n] = 0.f;

    const float Ad0 = Ad[0];
    bool fastA = true;
    #pragma unroll
    for (int n = 1; n < DS; ++n)
        fastA = fastA && (fabsf(Ad[n] - (float)(n + 1) * Ad0)
                          <= 1e-4f * (float)(n + 1) * fabsf(Ad0));

    size_t base = (size_t)(c * CH) * DI + d;
    float S = 0.f;
    if (fastA) {
        for (int tt = 0; tt < CH; ++tt, base += DI) {
            const float dtv = bf2f(dt[base]);
            const float xv  = bf2f(xcv[base]);
            S += dtv;
            const float xdt = xv * dtv;
            float e[16];
            POWTREE(e, __expf(Ad0 * dtv));
            #pragma unroll
            for (int n = 0; n < DS; ++n)
                h[n] = fmaf(h[n], e[n], xdt * Bs[tt][n]);
        }
    } else {
        for (int tt = 0; tt < CH; ++tt, base += DI) {
            const float dtv = bf2f(dt[base]);
            const float xv  = bf2f(xcv[base]);
            S += dtv;
            const float xdt = xv * dtv;
            #pragma unroll
            for (int n = 0; n < DS; ++n)
                h[n] = fmaf(h[n], __expf(Ad[n] * dtv), xdt * Bs[tt][n]);
        }
    }

    u16* o = hloc + ((size_t)c * DI + d) * DS;
    #pragma unroll
    for (int q = 0; q < 4; ++q) {
        ushort4 pk;
        pk.x = f2bf(h[q * 4 + 0]); pk.y = f2bf(h[q * 4 + 1]);
        pk.z = f2bf(h[q * 4 + 2]); pk.w = f2bf(h[q * 4 + 3]);
        *(ushort4*)(o + q * 4) = pk;
    }
    Ssum[c * DI + d] = S;
}

// ---------------------------------------------------------------------------
// Scan pass 2: scan the NC chunk carries per (d,n); hc bf16 in-place.
// ---------------------------------------------------------------------------
__global__ __launch_bounds__(256)
void scan2_k(u16* hc, const float* __restrict__ Ssum,
             const float* __restrict__ Aneg)
{
    const int p = blockIdx.x * 256 + threadIdx.x;
    if (p >= DI * DS) return;
    const int d = p >> 4;
    const float Ad = Aneg[p];
    float h = 0.f;
    for (int c = 0; c < NC; ++c) {
        const size_t o = (size_t)c * DI * DS + p;
        const float hl = bf2f(hc[o]);     // local state
        hc[o] = f2bf(h);                  // overwrite with carry-in
        h = fmaf(h, __expf(Ad * Ssum[c * DI + d]), hl);
    }
}

// ---------------------------------------------------------------------------
// Scan pass 3: replay with carry-in; emit yz bf16 into dead x-half of xzb.
// Same fast-path power tree as scan1.
// ---------------------------------------------------------------------------
__global__ __launch_bounds__(256)
void scan3_k(const u16* __restrict__ dt, const u16* __restrict__ xcv,
             const float* __restrict__ dtbc, const float* __restrict__ Aneg,
             const u16* __restrict__ carry, const float* __restrict__ Dp,
             const u16* __restrict__ xzb, u16* __restrict__ ybf)
{
    __shared__ float Bs[CH][DS];
    __shared__ float Cs[CH][DS];
    const int c = blockIdx.y;
    const int d = blockIdx.x * 256 + threadIdx.x;

    for (int i = threadIdx.x; i < CH * DS; i += 256) {
        int tt = i >> 4, n = i & 15;
        Bs[tt][n] = dtbc[(size_t)(c * CH + tt) * NCOMB + 48 + n];
        Cs[tt][n] = dtbc[(size_t)(c * CH + tt) * NCOMB + 64 + n];
    }
    __syncthreads();

    float Ad[DS], h[DS];
    const u16* co = carry + ((size_t)c * DI + d) * DS;
    #pragma unroll
    for (int q = 0; q < 4; ++q) {
        const ushort4 cv = *(const ushort4*)(co + q * 4);
        h[q * 4 + 0] = bf2f(cv.x); h[q * 4 + 1] = bf2f(cv.y);
        h[q * 4 + 2] = bf2f(cv.z); h[q * 4 + 3] = bf2f(cv.w);
    }
    #pragma unroll
    for (int q = 0; q < 4; ++q)
        *(float4*)&Ad[q * 4] = *(const float4*)(Aneg + (size_t)d * DS + q * 4);
    const float Dv = Dp[d];

    const float Ad0 = Ad[0];
    bool fastA = true;
    #pragma unroll
    for (int n = 1; n < DS; ++n)
        fastA = fastA && (fabsf(Ad[n] - (float)(n + 1) * Ad0)
                          <= 1e-4f * (float)(n + 1) * fabsf(Ad0));

    int t = c * CH;
    if (fastA) {
        for (int tt = 0; tt < CH; ++tt, ++t) {
            const size_t o = (size_t)t * DI + d;
            const float dtv = bf2f(dt[o]);
            const float xv  = bf2f(xcv[o]);
            const float xdt = xv * dtv;
            float y = Dv * xv;
            float e[16];
            POWTREE(e, __expf(Ad0 * dtv));
            #pragma unroll
            for (int n = 0; n < DS; ++n) {
                h[n] = fmaf(h[n], e[n], xdt * Bs[tt][n]);
                y = fmaf(h[n], Cs[tt][n], y);
            }
            const float z = bf2f(xzb[(size_t)t * XZROW + DI + d]);
            ybf[(size_t)t * XZROW + d] = f2bf(y * silu_f(z));
        }
    } else {
        for (int tt = 0; tt < CH; ++tt, ++t) {
            const size_t o = (size_t)t * DI + d;
            const float dtv = bf2f(dt[o]);
            const float xv  = bf2f(xcv[o]);
            const float xdt = xv * dtv;
            float y = Dv * xv;
            #pragma unroll
            for (int n = 0; n < DS; ++n) {
                h[n] = fmaf(h[n], __expf(Ad[n] * dtv), xdt * Bs[tt][n]);
                y = fmaf(h[n], Cs[tt][n], y);
            }
            const float z = bf2f(xzb[(size_t)t * XZROW + DI + d]);
            ybf[(size_t)t * XZROW + d] = f2bf(y * silu_f(z));
        }
    }
}

// ---------------------------------------------------------------------------
extern "C" void kernel_launch(void* const* d_in, const int* in_sizes, int n_in,
                              void* d_out, int out_size, void* d_ws, size_t ws_size,
                              hipStream_t stream)
{
    const float* u    = (const float*)d_in[0];
    const float* Wip  = (const float*)d_in[1];
    const float* cw   = (const float*)d_in[2];
    const float* cb   = (const float*)d_in[3];
    const float* xdt  = (const float*)d_in[4];
    const float* xbw  = (const float*)d_in[5];
    const float* xcw  = (const float*)d_in[6];
    const float* dtw  = (const float*)d_in[7];
    const float* dtb  = (const float*)d_in[8];
    const float* alog = (const float*)d_in[9];
    const float* Dp   = (const float*)d_in[10];
    const float* Wop  = (const float*)d_in[11];
    float* out = (float*)d_out;

    // workspace layout (float units) — ~75 MB
    float* ws   = (float*)d_ws;
    u16*   xzb  = (u16*)ws;                          // [4096][3072] bf16
    u16*   xcvb = (u16*)(ws + (size_t)L * XZROW / 2);// [4096][1536] bf16
    float* dtbc = ws + (size_t)L * XZROW / 2
                     + (size_t)L * DI / 2;           // L*NCOMB fp32
    float* dty  = dtbc + (size_t)L * NCOMB;          // L*DI region (g2p, then dt bf16)
    float* Wt   = dty  + (size_t)L * DI;             // DI*NCOMB
    u16*   hc   = (u16*)(Wt + (size_t)DI * NCOMB);   // NC*DI*DS u16
    float* Ssum = Wt + (size_t)DI * NCOMB
                     + (size_t)NC * DI * DS / 2;     // NC*DI
    float* Aneg = Ssum + (size_t)NC * DI;            // DI*DS
    u16*   wopb = (u16*)(Aneg + NA);                 // [768][1536] bf16

    // aliases into regions dead at time of use
    u16*   ubf  = xcvb;                        // [4096][768]  (dead until conv)
    u16*   Wipb = xcvb + (size_t)L * DM;       // [3072][768]  (dead until conv)
    float* g2p  = dty;                         // [16][4096][80] (dead after reduce)
    u16*   dtbf = (u16*)dty;                   // [4096][1536] bf16 dt (after reduce)
    u16*   ybf  = xzb;                         // x-half of xzb rows (dead after conv)

    const dim3 blk(256);

    // 1) early packs: ubf, Wipb, wopb (bf16), Wt, Aneg
    pack_early_k<<<(NU4 + NW4 + NO4 + NWT + NA + 255) / 256, blk, 0, stream>>>(
        u, Wip, Wop, xdt, xbw, xcw, alog, ubf, Wipb, wopb, Wt, Aneg);

    // 2) xz = u @ in_proj_w^T   [4096, 3072] bf16 out (bf16 MFMA, K=768)
    gemm_bf16_bt_o16<<<dim3((2 * DI) / 128, L / 128), blk, 0, stream>>>(
        ubf, Wipb, xzb, L, 2 * DI, DM);

    // 3) causal conv + SiLU -> xcvb (bf16 in/out, 8 ch/thread)
    conv_silu_v8<<<(L * (DI / 8) + 255) / 256, blk, 0, stream>>>(xzb, cw, cb, xcvb);

    // 4) [dt_rank|B|C] = xcvb @ Wt via split-K (partials in dty region)
    gemm2_splitk<<<dim3(L / 64, G2_S), blk, 0, stream>>>(xcvb, Wt, g2p);
    gemm2_reduce<<<(L * NCOMB + 255) / 256, blk, 0, stream>>>(g2p, dtbc);

    // 5) dt = softplus(dtr @ dtw^T + dtb) -> bf16 (overwrites g2p region)
    dt_k<<<dim3(DI / 256, L / 32), blk, 0, stream>>>(dtbc, dtw, dtb, dtbf);

    // 6-8) chunked selective scan (CH=32, 128 chunks)
    scan1_k<<<dim3(DI / 256, NC), blk, 0, stream>>>(
        dtbf, xcvb, dtbc, Aneg, hc, Ssum);
    scan2_k<<<(DI * DS) / 256, blk, 0, stream>>>(hc, Ssum, Aneg);
    scan3_k<<<dim3(DI / 256, NC), blk, 0, stream>>>(
        dtbf, xcvb, dtbc, Aneg, hc, Dp, xzb, ybf);

    // 9) out = yz @ out_proj_w^T   [4096, 768]  (bf16 MFMA; A strided in xzb)
    gemm_bf16_bt_n64<<<dim3(DM / 64, L / 128), blk, 0, stream>>>(
        ybf, XZROW, wopb, DI, out, L, DM, DI);
}

// Round 14
// 215.827 us; speedup vs baseline: 2.6274x; 1.0362x over previous
//
#include <hip/hip_runtime.h>
#include <math.h>

// Problem constants (UnifiedMambaBlock, B=1)
#define L      4096
#define DM     768
#define DI     1536
#define DS     16
#define DR     48
#define NCOMB  80     // 48 dt_rank + 16 B + 16 C
#define CH     32     // scan chunk length
#define NC     128    // number of chunks (L / CH)
#define G2_S   8      // GEMM2 K-splits (each block: 2 x 96-chunks)
#define G2_KC  96
#define XZROW  3072   // xz row stride in u16 (bf16 [4096][3072])

typedef unsigned short u16;
typedef unsigned int   u32;
typedef __attribute__((ext_vector_type(8))) short bf16x8;   // 8 bf16 = 4 VGPRs
typedef __attribute__((ext_vector_type(8))) unsigned short u16x8;
typedef __attribute__((ext_vector_type(4))) float f32x4;

__device__ __forceinline__ float silu_f(float v) { return v / (1.f + __expf(-v)); }

__device__ __forceinline__ u16 f2bf(float f) {              // RNE f32 -> bf16
    u32 u = __float_as_uint(f);
    return (u16)((u + 0x7fffu + ((u >> 16) & 1u)) >> 16);
}
__device__ __forceinline__ float bf2f(u16 h) {
    return __uint_as_float(((u32)h) << 16);
}

__device__ __forceinline__ float softplus_f(float s) {
    return (s > 20.f) ? s : log1pf(expf(s));
}

__device__ __forceinline__ void gl_lds16(const u16* g, u16* l) {
    __builtin_amdgcn_global_load_lds(
        (const __attribute__((address_space(1))) void*)g,
        (__attribute__((address_space(3))) void*)l, 16, 0, 0);
}

// Power tree: given e1 = exp(a), fill e[n] = e1^(n+1), n=0..15 (depth-4 muls)
#define POWTREE(e, e1) {                                                       \
    e[0] = (e1);                                                               \
    e[1] = e[0]*e[0];  e[2] = e[1]*e[0];  e[3] = e[1]*e[1];                    \
    e[4] = e[3]*e[0];  e[5] = e[2]*e[2];  e[6] = e[3]*e[2];  e[7] = e[3]*e[3]; \
    e[8] = e[7]*e[0];  e[9] = e[7]*e[1];  e[10]= e[7]*e[2];  e[11]= e[7]*e[3]; \
    e[12]= e[7]*e[4];  e[13]= e[7]*e[5];  e[14]= e[7]*e[6];  e[15]= e[7]*e[7]; }

// XCD-aware bijective block swizzle (requires nwg % 8 == 0)
#define XCD_SWZ(bx, by, gridx, gridy) {                                        \
    const int lin = (by) * (gridx) + (bx);                                     \
    const int cpx = ((gridx) * (gridy)) >> 3;                                  \
    const int swz = (lin & 7) * cpx + (lin >> 3);                              \
    bx = swz % (gridx);  by = swz / (gridx); }

// ---------------------------------------------------------------------------
// bf16 MFMA GEMM (m97 structure), BF16 OUTPUT: Cb[M][N] bf16 = A @ W^T.
// ---------------------------------------------------------------------------
__global__ __launch_bounds__(256)
void gemm_bf16_bt_o16(const u16* __restrict__ A, const u16* __restrict__ W,
                      u16* __restrict__ Cb, int M, int N, int K)
{
    __shared__ u16 As[2][128 * 32];
    __shared__ u16 Bs[2][128 * 32];

    const int tid  = threadIdx.x;
    const int lane = tid & 63;
    const int wave = tid >> 6;
    const int wr   = (wave >> 1) * 64;
    const int wc   = (wave & 1) * 64;

    int bx = blockIdx.x, by = blockIdx.y;
    XCD_SWZ(bx, by, gridDim.x, gridDim.y);
    const int m0 = by * 128;
    const int n0 = bx * 128;

    const int r0 = tid >> 2;
    const int k0 = (tid & 3) * 8;

    const int frow = lane & 15;
    const int fk   = (lane >> 4) * 8;

    f32x4 acc[4][4];
    #pragma unroll
    for (int i = 0; i < 4; ++i)
        #pragma unroll
        for (int j = 0; j < 4; ++j)
            acc[i][j] = (f32x4){0.f, 0.f, 0.f, 0.f};

    const int NT = K >> 5;

#define STAGE(buf, kk) {                                                       \
        const u16* ga = A + (size_t)(m0 + r0) * K + (kk) + k0;                 \
        const u16* gw = W + (size_t)(n0 + r0) * K + (kk) + k0;                 \
        gl_lds16(ga,                   &As[buf][tid * 8]);                     \
        gl_lds16(ga + (size_t)64 * K,  &As[buf][2048 + tid * 8]);              \
        gl_lds16(gw,                   &Bs[buf][tid * 8]);                     \
        gl_lds16(gw + (size_t)64 * K,  &Bs[buf][2048 + tid * 8]); }

    STAGE(0, 0);
    __syncthreads();

    for (int t = 0; t < NT; ++t) {
        const int b = t & 1;
        if (t + 1 < NT) STAGE(b ^ 1, (t + 1) << 5);

        bf16x8 af[4], bw[4];
        #pragma unroll
        for (int m = 0; m < 4; ++m)
            af[m] = *(const bf16x8*)&As[b][(wr + m * 16 + frow) * 32 + fk];
        #pragma unroll
        for (int n = 0; n < 4; ++n)
            bw[n] = *(const bf16x8*)&Bs[b][(wc + n * 16 + frow) * 32 + fk];

        #pragma unroll
        for (int m = 0; m < 4; ++m)
            #pragma unroll
            for (int n = 0; n < 4; ++n)
                acc[m][n] = __builtin_amdgcn_mfma_f32_16x16x32_bf16(
                    af[m], bw[n], acc[m][n], 0, 0, 0);

        __syncthreads();
    }
#undef STAGE

    const int crow = (lane >> 4) * 4;
    const int ccol = lane & 15;
    #pragma unroll
    for (int m = 0; m < 4; ++m)
        #pragma unroll
        for (int n = 0; n < 4; ++n)
            #pragma unroll
            for (int r = 0; r < 4; ++r)
                Cb[(size_t)(m0 + wr + m * 16 + crow + r) * N
                   + n0 + wc + n * 16 + ccol] = f2bf(acc[m][n][r]);
}

// ---------------------------------------------------------------------------
// bf16 MFMA GEMM with strided rows (lda/ldw in u16 elems), 128(M)x64(N) tile,
// fp32 output. Used for GEMM4.
// ---------------------------------------------------------------------------
__global__ __launch_bounds__(256)
void gemm_bf16_bt_n64(const u16* __restrict__ A, int lda,
                      const u16* __restrict__ W, int ldw,
                      float* __restrict__ C, int M, int N, int K)
{
    __shared__ u16 As[2][128 * 32];
    __shared__ u16 Bs[2][64 * 32];

    const int tid  = threadIdx.x;
    const int lane = tid & 63;
    const int wave = tid >> 6;
    const int wr   = (wave >> 1) * 64;
    const int wc   = (wave & 1) * 32;

    int bx = blockIdx.x, by = blockIdx.y;
    XCD_SWZ(bx, by, gridDim.x, gridDim.y);
    const int m0 = by * 128;
    const int n0 = bx * 64;

    const int r0 = tid >> 2;
    const int k0 = (tid & 3) * 8;

    const int frow = lane & 15;
    const int fk   = (lane >> 4) * 8;

    f32x4 acc[4][2];
    #pragma unroll
    for (int i = 0; i < 4; ++i)
        #pragma unroll
        for (int j = 0; j < 2; ++j)
            acc[i][j] = (f32x4){0.f, 0.f, 0.f, 0.f};

    const int NT = K >> 5;

#define STG(buf, kk) {                                                         \
        const u16* ga = A + (size_t)(m0 + r0) * lda + (kk) + k0;               \
        gl_lds16(ga,                     &As[buf][tid * 8]);                   \
        gl_lds16(ga + (size_t)64 * lda,  &As[buf][2048 + tid * 8]);            \
        gl_lds16(W + (size_t)(n0 + r0) * ldw + (kk) + k0, &Bs[buf][tid * 8]); }

    STG(0, 0);
    __syncthreads();

    for (int t = 0; t < NT; ++t) {
        const int b = t & 1;
        if (t + 1 < NT) STG(b ^ 1, (t + 1) << 5);

        bf16x8 af[4], bw[2];
        #pragma unroll
        for (int m = 0; m < 4; ++m)
            af[m] = *(const bf16x8*)&As[b][(wr + m * 16 + frow) * 32 + fk];
        #pragma unroll
        for (int n = 0; n < 2; ++n)
            bw[n] = *(const bf16x8*)&Bs[b][(wc + n * 16 + frow) * 32 + fk];

        #pragma unroll
        for (int m = 0; m < 4; ++m)
            #pragma unroll
            for (int n = 0; n < 2; ++n)
                acc[m][n] = __builtin_amdgcn_mfma_f32_16x16x32_bf16(
                    af[m], bw[n], acc[m][n], 0, 0, 0);

        __syncthreads();
    }
#undef STG

    const int crow = (lane >> 4) * 4;
    const int ccol = lane & 15;
    #pragma unroll
    for (int m = 0; m < 4; ++m)
        #pragma unroll
        for (int n = 0; n < 2; ++n)
            #pragma unroll
            for (int r = 0; r < 4; ++r)
                C[(size_t)(m0 + wr + m * 16 + crow + r) * N
                  + n0 + wc + n * 16 + ccol] = acc[m][n][r];
}

// ---------------------------------------------------------------------------
// Early pack: u->ubf, Wip->Wipb, Wop->wopb (bf16), [xdt;xb;xc]^T->Wt (fp32),
// Aneg = -exp(A_log)
// ---------------------------------------------------------------------------
#define NU4  (L * DM / 4)            // 786432
#define NW4  (2 * DI * DM / 4)       // 589824
#define NO4  (DM * DI / 4)           // 294912
#define NWT  (DI * NCOMB)            // 122880
#define NA   (DI * DS)               // 24576
__global__ __launch_bounds__(256)
void pack_early_k(const float* __restrict__ u, const float* __restrict__ Wip,
                  const float* __restrict__ Wop,
                  const float* __restrict__ xdt, const float* __restrict__ xb,
                  const float* __restrict__ xc, const float* __restrict__ alog,
                  u16* __restrict__ ubf, u16* __restrict__ Wipb,
                  u16* __restrict__ wopb,
                  float* __restrict__ Wt, float* __restrict__ Aneg)
{
    int i = blockIdx.x * 256 + threadIdx.x;
    if (i < NU4) {
        const float4 v = ((const float4*)u)[i];
        ushort4 o; o.x = f2bf(v.x); o.y = f2bf(v.y); o.z = f2bf(v.z); o.w = f2bf(v.w);
        ((ushort4*)ubf)[i] = o;
        return;
    }
    i -= NU4;
    if (i < NW4) {
        const float4 v = ((const float4*)Wip)[i];
        ushort4 o; o.x = f2bf(v.x); o.y = f2bf(v.y); o.z = f2bf(v.z); o.w = f2bf(v.w);
        ((ushort4*)Wipb)[i] = o;
        return;
    }
    i -= NW4;
    if (i < NO4) {
        const float4 v = ((const float4*)Wop)[i];
        ushort4 o; o.x = f2bf(v.x); o.y = f2bf(v.y); o.z = f2bf(v.z); o.w = f2bf(v.w);
        ((ushort4*)wopb)[i] = o;
        return;
    }
    i -= NO4;
    if (i < NWT) {
        const int k = i / NCOMB, n = i - k * NCOMB;
        float v;
        if (n < 48)      v = xdt[n * DI + k];
        else if (n < 64) v = xb[(n - 48) * DI + k];
        else             v = xc[(n - 64) * DI + k];
        Wt[i] = v;
        return;
    }
    i -= NWT;
    if (i < NA)
        Aneg[i] = -expf(alog[i]);
}

// ---------------------------------------------------------------------------
// Causal depthwise conv (width 4) + bias + SiLU. bf16 in/out, 8 ch/thread.
// ---------------------------------------------------------------------------
__global__ __launch_bounds__(256)
void conv_silu_v8(const u16* __restrict__ xzb, const float* __restrict__ cw,
                  const float* __restrict__ cb, u16* __restrict__ xcvb)
{
    int idx = blockIdx.x * 256 + threadIdx.x;
    if (idx >= L * (DI / 8)) return;
    const int t = idx / (DI / 8);
    const int q = idx - t * (DI / 8);
    const int d = q * 8;

    float w[8][4];
    #pragma unroll
    for (int j = 0; j < 8; ++j)
        *(float4*)w[j] = ((const float4*)cw)[d + j];

    float acc[8];
    {
        const float4 b0 = ((const float4*)cb)[q * 2];
        const float4 b1 = ((const float4*)cb)[q * 2 + 1];
        acc[0] = b0.x; acc[1] = b0.y; acc[2] = b0.z; acc[3] = b0.w;
        acc[4] = b1.x; acc[5] = b1.y; acc[6] = b1.z; acc[7] = b1.w;
    }

    const u16* base = xzb + d;
    #pragma unroll
    for (int j = 0; j < 4; ++j) {
        const int tt = t - 3 + j;
        if (tt >= 0) {
            const u16x8 x8 = *(const u16x8*)(base + (size_t)tt * XZROW);
            #pragma unroll
            for (int k = 0; k < 8; ++k)
                acc[k] = fmaf(w[k][j], bf2f(x8[k]), acc[k]);
        }
    }
    u16x8 o;
    #pragma unroll
    for (int k = 0; k < 8; ++k)
        o[k] = f2bf(silu_f(acc[k]));
    ((u16x8*)xcvb)[idx] = o;
}

// ---------------------------------------------------------------------------
// GEMM2 split-K: part[s][L][80] = xcvb[L][K-slice] @ Wt[K-slice][80]
// G2_S=8 splits; each block processes TWO successive 96-wide K-chunks
// (fixed order -> deterministic), halving partial traffic vs 16 splits.
// ---------------------------------------------------------------------------
__global__ __launch_bounds__(256)
void gemm2_splitk(const u16* __restrict__ A, const float* __restrict__ Wt,
                  float* __restrict__ part)
{
    __shared__ float As[G2_KC][65];     // +1 pad
    __shared__ float Ws[G2_KC][80];

    const int tid  = threadIdx.x;
    const int m0   = blockIdx.x * 64;

    const int g  = tid >> 6;
    const int r  = tid & 63;
    const int c0 = g * 20;

    float acc[20];
    #pragma unroll
    for (int j = 0; j < 20; ++j) acc[j] = 0.f;

    #pragma unroll
    for (int half = 0; half < 2; ++half) {
        const int koff = (blockIdx.y * 2 + half) * G2_KC;
        if (half) __syncthreads();          // protect LDS before overwrite

        {
            const int rr = tid >> 2, cg = tid & 3;
            #pragma unroll
            for (int j = 0; j < 6; ++j) {
                const int kk = (j * 4 + cg) * 4;
                const ushort4 v = *(const ushort4*)(A + (size_t)(m0 + rr) * DI + koff + kk);
                As[kk + 0][rr] = bf2f(v.x); As[kk + 1][rr] = bf2f(v.y);
                As[kk + 2][rr] = bf2f(v.z); As[kk + 3][rr] = bf2f(v.w);
            }
        }
        for (int i = tid; i < G2_KC * 80; i += 256)
            (&Ws[0][0])[i] = Wt[(size_t)koff * 80 + i];
        __syncthreads();

        #pragma unroll 2
        for (int k = 0; k < G2_KC; ++k) {
            const float a = As[k][r];
            #pragma unroll
            for (int q = 0; q < 5; ++q) {
                const float4 w = *(const float4*)&Ws[k][c0 + q * 4];
                acc[q * 4 + 0] = fmaf(a, w.x, acc[q * 4 + 0]);
                acc[q * 4 + 1] = fmaf(a, w.y, acc[q * 4 + 1]);
                acc[q * 4 + 2] = fmaf(a, w.z, acc[q * 4 + 2]);
                acc[q * 4 + 3] = fmaf(a, w.w, acc[q * 4 + 3]);
            }
        }
    }

    float* p = part + (size_t)blockIdx.y * (L * NCOMB)
                    + (size_t)(m0 + r) * NCOMB + c0;
    #pragma unroll
    for (int q = 0; q < 5; ++q)
        ((float4*)p)[q] = make_float4(acc[q * 4], acc[q * 4 + 1],
                                      acc[q * 4 + 2], acc[q * 4 + 3]);
}

__global__ __launch_bounds__(256)
void gemm2_reduce(const float* __restrict__ part, float* __restrict__ dtbc)
{
    int i = blockIdx.x * 256 + threadIdx.x;
    if (i >= L * NCOMB) return;
    float s = 0.f;
    #pragma unroll
    for (int j = 0; j < G2_S; ++j)
        s += part[(size_t)j * L * NCOMB + i];
    dtbc[i] = s;
}

// ---------------------------------------------------------------------------
// dt = softplus(dtr @ dtw^T + dtb), stored bf16. Block = 256 ch x 32 t.
// ---------------------------------------------------------------------------
__global__ __launch_bounds__(256)
void dt_k(const float* __restrict__ dtbc, const float* __restrict__ dtw,
          const float* __restrict__ dtb, u16* __restrict__ dt)
{
    __shared__ float dtr_s[32][48];
    const int tid = threadIdx.x;
    const int d   = blockIdx.x * 256 + tid;
    const int t0  = blockIdx.y * 32;

    for (int i = tid; i < 384; i += 256) {
        const int r = i / 12, c = (i - r * 12) * 4;
        const float4 v = *(const float4*)(dtbc + (size_t)(t0 + r) * NCOMB + c);
        *(float4*)&dtr_s[r][c] = v;
    }
    __syncthreads();

    float w[48];
    #pragma unroll
    for (int j = 0; j < 12; ++j) {
        const float4 v = *(const float4*)(dtw + (size_t)d * DR + j * 4);
        w[j * 4 + 0] = v.x; w[j * 4 + 1] = v.y;
        w[j * 4 + 2] = v.z; w[j * 4 + 3] = v.w;
    }
    const float b = dtb[d];

    for (int t = 0; t < 32; ++t) {
        float s = b;
        #pragma unroll
        for (int j = 0; j < 12; ++j) {
            const float4 v = *(const float4*)&dtr_s[t][j * 4];
            s = fmaf(v.x, w[j * 4 + 0], s);
            s = fmaf(v.y, w[j * 4 + 1], s);
            s = fmaf(v.z, w[j * 4 + 2], s);
            s = fmaf(v.w, w[j * 4 + 3], s);
        }
        dt[(size_t)(t0 + t) * DI + d] = f2bf(softplus_f(s));
    }
}

// ---------------------------------------------------------------------------
// Scan pass 1: per-chunk local states (bf16) + dt chunk-sums. CH=32.
// Fast path: Ad[n] = (n+1)*Ad[0] (verified per-thread) -> 1 exp + power tree.
// ---------------------------------------------------------------------------
__global__ __launch_bounds__(256)
void scan1_k(const u16* __restrict__ dt, const u16* __restrict__ xcv,
             const float* __restrict__ dtbc, const float* __restrict__ Aneg,
             u16* __restrict__ hloc, float* __restrict__ Ssum)
{
    __shared__ float Bs[CH][DS];
    const int c = blockIdx.y;
    const int d = blockIdx.x * 256 + threadIdx.x;

    for (int i = threadIdx.x; i < CH * DS; i += 256) {
        int tt = i >> 4, n = i & 15;
        Bs[tt][n] = dtbc[(size_t)(c * CH + tt) * NCOMB + 48 + n];
    }
    __syncthreads();

    float Ad[DS], h[DS];
    #pragma unroll
    for (int q = 0; q < 4; ++q)
        *(float4*)&Ad[q * 4] = *(const float4*)(Aneg + (size_t)d * DS + q * 4);
    #pragma unroll
    for (int n = 0; n < DS; ++n) h[n] = 0.f;

    const float Ad0 = Ad[0];
    bool fastA = true;
    #pragma unroll
    for (int n = 1; n < DS; ++n)
        fastA = fastA && (fabsf(Ad[n] - (float)(n + 1) * Ad0)
                          <= 1e-4f * (float)(n + 1) * fabsf(Ad0));

    size_t base = (size_t)(c * CH) * DI + d;
    float S = 0.f;
    if (fastA) {
        for (int tt = 0; tt < CH; ++tt, base += DI) {
            const float dtv = bf2f(dt[base]);
            const float xv  = bf2f(xcv[base]);
            S += dtv;
            const float xdt = xv * dtv;
            float e[16];
            POWTREE(e, __expf(Ad0 * dtv));
            #pragma unroll
            for (int n = 0; n < DS; ++n)
                h[n] = fmaf(h[n], e[n], xdt * Bs[tt][n]);
        }
    } else {
        for (int tt = 0; tt < CH; ++tt, base += DI) {
            const float dtv = bf2f(dt[base]);
            const float xv  = bf2f(xcv[base]);
            S += dtv;
            const float xdt = xv * dtv;
            #pragma unroll
            for (int n = 0; n < DS; ++n)
                h[n] = fmaf(h[n], __expf(Ad[n] * dtv), xdt * Bs[tt][n]);
        }
    }

    u16* o = hloc + ((size_t)c * DI + d) * DS;
    #pragma unroll
    for (int q = 0; q < 4; ++q) {
        ushort4 pk;
        pk.x = f2bf(h[q * 4 + 0]); pk.y = f2bf(h[q * 4 + 1]);
        pk.z = f2bf(h[q * 4 + 2]); pk.w = f2bf(h[q * 4 + 3]);
        *(ushort4*)(o + q * 4) = pk;
    }
    Ssum[c * DI + d] = S;
}

// ---------------------------------------------------------------------------
// Scan pass 2: scan the NC chunk carries per (d,n); hc bf16 in-place.
// ---------------------------------------------------------------------------
__global__ __launch_bounds__(256)
void scan2_k(u16* hc, const float* __restrict__ Ssum,
             const float* __restrict__ Aneg)
{
    const int p = blockIdx.x * 256 + threadIdx.x;
    if (p >= DI * DS) return;
    const int d = p >> 4;
    const float Ad = Aneg[p];
    float h = 0.f;
    for (int c = 0; c < NC; ++c) {
        const size_t o = (size_t)c * DI * DS + p;
        const float hl = bf2f(hc[o]);     // local state
        hc[o] = f2bf(h);                  // overwrite with carry-in
        h = fmaf(h, __expf(Ad * Ssum[c * DI + d]), hl);
    }
}

// ---------------------------------------------------------------------------
// Scan pass 3: replay with carry-in; emit yz bf16 into dead x-half of xzb.
// ---------------------------------------------------------------------------
__global__ __launch_bounds__(256)
void scan3_k(const u16* __restrict__ dt, const u16* __restrict__ xcv,
             const float* __restrict__ dtbc, const float* __restrict__ Aneg,
             const u16* __restrict__ carry, const float* __restrict__ Dp,
             const u16* __restrict__ xzb, u16* __restrict__ ybf)
{
    __shared__ float Bs[CH][DS];
    __shared__ float Cs[CH][DS];
    const int c = blockIdx.y;
    const int d = blockIdx.x * 256 + threadIdx.x;

    for (int i = threadIdx.x; i < CH * DS; i += 256) {
        int tt = i >> 4, n = i & 15;
        Bs[tt][n] = dtbc[(size_t)(c * CH + tt) * NCOMB + 48 + n];
        Cs[tt][n] = dtbc[(size_t)(c * CH + tt) * NCOMB + 64 + n];
    }
    __syncthreads();

    float Ad[DS], h[DS];
    const u16* co = carry + ((size_t)c * DI + d) * DS;
    #pragma unroll
    for (int q = 0; q < 4; ++q) {
        const ushort4 cv = *(const ushort4*)(co + q * 4);
        h[q * 4 + 0] = bf2f(cv.x); h[q * 4 + 1] = bf2f(cv.y);
        h[q * 4 + 2] = bf2f(cv.z); h[q * 4 + 3] = bf2f(cv.w);
    }
    #pragma unroll
    for (int q = 0; q < 4; ++q)
        *(float4*)&Ad[q * 4] = *(const float4*)(Aneg + (size_t)d * DS + q * 4);
    const float Dv = Dp[d];

    const float Ad0 = Ad[0];
    bool fastA = true;
    #pragma unroll
    for (int n = 1; n < DS; ++n)
        fastA = fastA && (fabsf(Ad[n] - (float)(n + 1) * Ad0)
                          <= 1e-4f * (float)(n + 1) * fabsf(Ad0));

    int t = c * CH;
    if (fastA) {
        for (int tt = 0; tt < CH; ++tt, ++t) {
            const size_t o = (size_t)t * DI + d;
            const float dtv = bf2f(dt[o]);
            const float xv  = bf2f(xcv[o]);
            const float xdt = xv * dtv;
            float y = Dv * xv;
            float e[16];
            POWTREE(e, __expf(Ad0 * dtv));
            #pragma unroll
            for (int n = 0; n < DS; ++n) {
                h[n] = fmaf(h[n], e[n], xdt * Bs[tt][n]);
                y = fmaf(h[n], Cs[tt][n], y);
            }
            const float z = bf2f(xzb[(size_t)t * XZROW + DI + d]);
            ybf[(size_t)t * XZROW + d] = f2bf(y * silu_f(z));
        }
    } else {
        for (int tt = 0; tt < CH; ++tt, ++t) {
            const size_t o = (size_t)t * DI + d;
            const float dtv = bf2f(dt[o]);
            const float xv  = bf2f(xcv[o]);
            const float xdt = xv * dtv;
            float y = Dv * xv;
            #pragma unroll
            for (int n = 0; n < DS; ++n) {
                h[n] = fmaf(h[n], __expf(Ad[n] * dtv), xdt * Bs[tt][n]);
                y = fmaf(h[n], Cs[tt][n], y);
            }
            const float z = bf2f(xzb[(size_t)t * XZROW + DI + d]);
            ybf[(size_t)t * XZROW + d] = f2bf(y * silu_f(z));
        }
    }
}

// ---------------------------------------------------------------------------
extern "C" void kernel_launch(void* const* d_in, const int* in_sizes, int n_in,
                              void* d_out, int out_size, void* d_ws, size_t ws_size,
                              hipStream_t stream)
{
    const float* u    = (const float*)d_in[0];
    const float* Wip  = (const float*)d_in[1];
    const float* cw   = (const float*)d_in[2];
    const float* cb   = (const float*)d_in[3];
    const float* xdt  = (const float*)d_in[4];
    const float* xbw  = (const float*)d_in[5];
    const float* xcw  = (const float*)d_in[6];
    const float* dtw  = (const float*)d_in[7];
    const float* dtb  = (const float*)d_in[8];
    const float* alog = (const float*)d_in[9];
    const float* Dp   = (const float*)d_in[10];
    const float* Wop  = (const float*)d_in[11];
    float* out = (float*)d_out;

    // workspace layout (float units) — ~70 MB
    float* ws   = (float*)d_ws;
    u16*   xzb  = (u16*)ws;                          // [4096][3072] bf16
    u16*   xcvb = (u16*)(ws + (size_t)L * XZROW / 2);// [4096][1536] bf16
    float* dtbc = ws + (size_t)L * XZROW / 2
                     + (size_t)L * DI / 2;           // L*NCOMB fp32
    float* dty  = dtbc + (size_t)L * NCOMB;          // L*DI region (g2p, then dt bf16)
    float* Wt   = dty  + (size_t)L * DI;             // DI*NCOMB
    u16*   hc   = (u16*)(Wt + (size_t)DI * NCOMB);   // NC*DI*DS u16
    float* Ssum = Wt + (size_t)DI * NCOMB
                     + (size_t)NC * DI * DS / 2;     // NC*DI
    float* Aneg = Ssum + (size_t)NC * DI;            // DI*DS
    u16*   wopb = (u16*)(Aneg + NA);                 // [768][1536] bf16

    // aliases into regions dead at time of use
    u16*   ubf  = xcvb;                        // [4096][768]  (dead until conv)
    u16*   Wipb = xcvb + (size_t)L * DM;       // [3072][768]  (dead until conv)
    float* g2p  = dty;                         // [8][4096][80] (dead after reduce)
    u16*   dtbf = (u16*)dty;                   // [4096][1536] bf16 dt (after reduce)
    u16*   ybf  = xzb;                         // x-half of xzb rows (dead after conv)

    const dim3 blk(256);

    // 1) early packs: ubf, Wipb, wopb (bf16), Wt, Aneg
    pack_early_k<<<(NU4 + NW4 + NO4 + NWT + NA + 255) / 256, blk, 0, stream>>>(
        u, Wip, Wop, xdt, xbw, xcw, alog, ubf, Wipb, wopb, Wt, Aneg);

    // 2) xz = u @ in_proj_w^T   [4096, 3072] bf16 out (bf16 MFMA, XCD swizzle)
    gemm_bf16_bt_o16<<<dim3((2 * DI) / 128, L / 128), blk, 0, stream>>>(
        ubf, Wipb, xzb, L, 2 * DI, DM);

    // 3) causal conv + SiLU -> xcvb (bf16 in/out, 8 ch/thread)
    conv_silu_v8<<<(L * (DI / 8) + 255) / 256, blk, 0, stream>>>(xzb, cw, cb, xcvb);

    // 4) [dt_rank|B|C] = xcvb @ Wt via split-K (8 splits x 2 chunks each)
    gemm2_splitk<<<dim3(L / 64, G2_S), blk, 0, stream>>>(xcvb, Wt, g2p);
    gemm2_reduce<<<(L * NCOMB + 255) / 256, blk, 0, stream>>>(g2p, dtbc);

    // 5) dt = softplus(dtr @ dtw^T + dtb) -> bf16 (overwrites g2p region)
    dt_k<<<dim3(DI / 256, L / 32), blk, 0, stream>>>(dtbc, dtw, dtb, dtbf);

    // 6-8) chunked selective scan (CH=32, 128 chunks)
    scan1_k<<<dim3(DI / 256, NC), blk, 0, stream>>>(
        dtbf, xcvb, dtbc, Aneg, hc, Ssum);
    scan2_k<<<(DI * DS) / 256, blk, 0, stream>>>(hc, Ssum, Aneg);
    scan3_k<<<dim3(DI / 256, NC), blk, 0, stream>>>(
        dtbf, xcvb, dtbc, Aneg, hc, Dp, xzb, ybf);

    // 9) out = yz @ out_proj_w^T   [4096, 768]  (bf16 MFMA, XCD swizzle)
    gemm_bf16_bt_n64<<<dim3(DM / 64, L / 128), blk, 0, stream>>>(
        ybf, XZROW, wopb, DI, out, L, DM, DI);
}

// Round 15
// 212.377 us; speedup vs baseline: 2.6701x; 1.0162x over previous
//
#include <hip/hip_runtime.h>
#include <math.h>

// Problem constants (UnifiedMambaBlock, B=1)
#define L      4096
#define DM     768
#define DI     1536
#define DS     16
#define DR     48
#define NCOMB  80     // 48 dt_rank + 16 B + 16 C
#define CH     32     // scan chunk length
#define NC     128    // number of chunks (L / CH)
#define G2_S   8      // GEMM2 K-splits (each block: 2 x 96-chunks)
#define G2_KC  96
#define XZROW  3072   // xz row stride in u16 (bf16 [4096][3072])

typedef unsigned short u16;
typedef unsigned int   u32;
typedef __attribute__((ext_vector_type(8))) short bf16x8;   // 8 bf16 = 4 VGPRs
typedef __attribute__((ext_vector_type(8))) unsigned short u16x8;
typedef __attribute__((ext_vector_type(4))) float f32x4;

__device__ __forceinline__ float silu_f(float v) { return v / (1.f + __expf(-v)); }

__device__ __forceinline__ u16 f2bf(float f) {              // RNE f32 -> bf16
    u32 u = __float_as_uint(f);
    return (u16)((u + 0x7fffu + ((u >> 16) & 1u)) >> 16);
}
__device__ __forceinline__ float bf2f(u16 h) {
    return __uint_as_float(((u32)h) << 16);
}

__device__ __forceinline__ float softplus_f(float s) {
    return (s > 20.f) ? s : log1pf(expf(s));
}

__device__ __forceinline__ void gl_lds16(const u16* g, u16* l) {
    __builtin_amdgcn_global_load_lds(
        (const __attribute__((address_space(1))) void*)g,
        (__attribute__((address_space(3))) void*)l, 16, 0, 0);
}

// Power tree: given e1 = exp(a), fill e[n] = e1^(n+1), n=0..15 (depth-4 muls)
#define POWTREE(e, e1) {                                                       \
    e[0] = (e1);                                                               \
    e[1] = e[0]*e[0];  e[2] = e[1]*e[0];  e[3] = e[1]*e[1];                    \
    e[4] = e[3]*e[0];  e[5] = e[2]*e[2];  e[6] = e[3]*e[2];  e[7] = e[3]*e[3]; \
    e[8] = e[7]*e[0];  e[9] = e[7]*e[1];  e[10]= e[7]*e[2];  e[11]= e[7]*e[3]; \
    e[12]= e[7]*e[4];  e[13]= e[7]*e[5];  e[14]= e[7]*e[6];  e[15]= e[7]*e[7]; }

// XCD-aware bijective block swizzle (requires nwg % 8 == 0)
#define XCD_SWZ(bx, by, gridx, gridy) {                                        \
    const int lin = (by) * (gridx) + (bx);                                     \
    const int cpx = ((gridx) * (gridy)) >> 3;                                  \
    const int swz = (lin & 7) * cpx + (lin >> 3);                              \
    bx = swz % (gridx);  by = swz / (gridx); }

// ---------------------------------------------------------------------------
// bf16 MFMA GEMM (m97 structure), BF16 OUTPUT: Cb[M][N] bf16 = A @ W^T.
// ---------------------------------------------------------------------------
__global__ __launch_bounds__(256)
void gemm_bf16_bt_o16(const u16* __restrict__ A, const u16* __restrict__ W,
                      u16* __restrict__ Cb, int M, int N, int K)
{
    __shared__ u16 As[2][128 * 32];
    __shared__ u16 Bs[2][128 * 32];

    const int tid  = threadIdx.x;
    const int lane = tid & 63;
    const int wave = tid >> 6;
    const int wr   = (wave >> 1) * 64;
    const int wc   = (wave & 1) * 64;

    int bx = blockIdx.x, by = blockIdx.y;
    XCD_SWZ(bx, by, gridDim.x, gridDim.y);
    const int m0 = by * 128;
    const int n0 = bx * 128;

    const int r0 = tid >> 2;
    const int k0 = (tid & 3) * 8;

    const int frow = lane & 15;
    const int fk   = (lane >> 4) * 8;

    f32x4 acc[4][4];
    #pragma unroll
    for (int i = 0; i < 4; ++i)
        #pragma unroll
        for (int j = 0; j < 4; ++j)
            acc[i][j] = (f32x4){0.f, 0.f, 0.f, 0.f};

    const int NT = K >> 5;

#define STAGE(buf, kk) {                                                       \
        const u16* ga = A + (size_t)(m0 + r0) * K + (kk) + k0;                 \
        const u16* gw = W + (size_t)(n0 + r0) * K + (kk) + k0;                 \
        gl_lds16(ga,                   &As[buf][tid * 8]);                     \
        gl_lds16(ga + (size_t)64 * K,  &As[buf][2048 + tid * 8]);              \
        gl_lds16(gw,                   &Bs[buf][tid * 8]);                     \
        gl_lds16(gw + (size_t)64 * K,  &Bs[buf][2048 + tid * 8]); }

    STAGE(0, 0);
    __syncthreads();

    for (int t = 0; t < NT; ++t) {
        const int b = t & 1;
        if (t + 1 < NT) STAGE(b ^ 1, (t + 1) << 5);

        bf16x8 af[4], bw[4];
        #pragma unroll
        for (int m = 0; m < 4; ++m)
            af[m] = *(const bf16x8*)&As[b][(wr + m * 16 + frow) * 32 + fk];
        #pragma unroll
        for (int n = 0; n < 4; ++n)
            bw[n] = *(const bf16x8*)&Bs[b][(wc + n * 16 + frow) * 32 + fk];

        #pragma unroll
        for (int m = 0; m < 4; ++m)
            #pragma unroll
            for (int n = 0; n < 4; ++n)
                acc[m][n] = __builtin_amdgcn_mfma_f32_16x16x32_bf16(
                    af[m], bw[n], acc[m][n], 0, 0, 0);

        __syncthreads();
    }
#undef STAGE

    const int crow = (lane >> 4) * 4;
    const int ccol = lane & 15;
    #pragma unroll
    for (int m = 0; m < 4; ++m)
        #pragma unroll
        for (int n = 0; n < 4; ++n)
            #pragma unroll
            for (int r = 0; r < 4; ++r)
                Cb[(size_t)(m0 + wr + m * 16 + crow + r) * N
                   + n0 + wc + n * 16 + ccol] = f2bf(acc[m][n][r]);
}

// ---------------------------------------------------------------------------
// bf16 MFMA GEMM with strided rows (lda/ldw in u16 elems), 128(M)x64(N) tile,
// fp32 output. Used for GEMM4.
// ---------------------------------------------------------------------------
__global__ __launch_bounds__(256)
void gemm_bf16_bt_n64(const u16* __restrict__ A, int lda,
                      const u16* __restrict__ W, int ldw,
                      float* __restrict__ C, int M, int N, int K)
{
    __shared__ u16 As[2][128 * 32];
    __shared__ u16 Bs[2][64 * 32];

    const int tid  = threadIdx.x;
    const int lane = tid & 63;
    const int wave = tid >> 6;
    const int wr   = (wave >> 1) * 64;
    const int wc   = (wave & 1) * 32;

    int bx = blockIdx.x, by = blockIdx.y;
    XCD_SWZ(bx, by, gridDim.x, gridDim.y);
    const int m0 = by * 128;
    const int n0 = bx * 64;

    const int r0 = tid >> 2;
    const int k0 = (tid & 3) * 8;

    const int frow = lane & 15;
    const int fk   = (lane >> 4) * 8;

    f32x4 acc[4][2];
    #pragma unroll
    for (int i = 0; i < 4; ++i)
        #pragma unroll
        for (int j = 0; j < 2; ++j)
            acc[i][j] = (f32x4){0.f, 0.f, 0.f, 0.f};

    const int NT = K >> 5;

#define STG(buf, kk) {                                                         \
        const u16* ga = A + (size_t)(m0 + r0) * lda + (kk) + k0;               \
        gl_lds16(ga,                     &As[buf][tid * 8]);                   \
        gl_lds16(ga + (size_t)64 * lda,  &As[buf][2048 + tid * 8]);            \
        gl_lds16(W + (size_t)(n0 + r0) * ldw + (kk) + k0, &Bs[buf][tid * 8]); }

    STG(0, 0);
    __syncthreads();

    for (int t = 0; t < NT; ++t) {
        const int b = t & 1;
        if (t + 1 < NT) STG(b ^ 1, (t + 1) << 5);

        bf16x8 af[4], bw[2];
        #pragma unroll
        for (int m = 0; m < 4; ++m)
            af[m] = *(const bf16x8*)&As[b][(wr + m * 16 + frow) * 32 + fk];
        #pragma unroll
        for (int n = 0; n < 2; ++n)
            bw[n] = *(const bf16x8*)&Bs[b][(wc + n * 16 + frow) * 32 + fk];

        #pragma unroll
        for (int m = 0; m < 4; ++m)
            #pragma unroll
            for (int n = 0; n < 2; ++n)
                acc[m][n] = __builtin_amdgcn_mfma_f32_16x16x32_bf16(
                    af[m], bw[n], acc[m][n], 0, 0, 0);

        __syncthreads();
    }
#undef STG

    const int crow = (lane >> 4) * 4;
    const int ccol = lane & 15;
    #pragma unroll
    for (int m = 0; m < 4; ++m)
        #pragma unroll
        for (int n = 0; n < 2; ++n)
            #pragma unroll
            for (int r = 0; r < 4; ++r)
                C[(size_t)(m0 + wr + m * 16 + crow + r) * N
                  + n0 + wc + n * 16 + ccol] = acc[m][n][r];
}

// ---------------------------------------------------------------------------
// Early pack: u->ubf, Wip->Wipb, Wop->wopb (bf16), [xdt;xb;xc]^T->Wt (fp32),
// Aneg = -exp(A_log)
// ---------------------------------------------------------------------------
#define NU4  (L * DM / 4)            // 786432
#define NW4  (2 * DI * DM / 4)       // 589824
#define NO4  (DM * DI / 4)           // 294912
#define NWT  (DI * NCOMB)            // 122880
#define NA   (DI * DS)               // 24576
__global__ __launch_bounds__(256)
void pack_early_k(const float* __restrict__ u, const float* __restrict__ Wip,
                  const float* __restrict__ Wop,
                  const float* __restrict__ xdt, const float* __restrict__ xb,
                  const float* __restrict__ xc, const float* __restrict__ alog,
                  u16* __restrict__ ubf, u16* __restrict__ Wipb,
                  u16* __restrict__ wopb,
                  float* __restrict__ Wt, float* __restrict__ Aneg)
{
    int i = blockIdx.x * 256 + threadIdx.x;
    if (i < NU4) {
        const float4 v = ((const float4*)u)[i];
        ushort4 o; o.x = f2bf(v.x); o.y = f2bf(v.y); o.z = f2bf(v.z); o.w = f2bf(v.w);
        ((ushort4*)ubf)[i] = o;
        return;
    }
    i -= NU4;
    if (i < NW4) {
        const float4 v = ((const float4*)Wip)[i];
        ushort4 o; o.x = f2bf(v.x); o.y = f2bf(v.y); o.z = f2bf(v.z); o.w = f2bf(v.w);
        ((ushort4*)Wipb)[i] = o;
        return;
    }
    i -= NW4;
    if (i < NO4) {
        const float4 v = ((const float4*)Wop)[i];
        ushort4 o; o.x = f2bf(v.x); o.y = f2bf(v.y); o.z = f2bf(v.z); o.w = f2bf(v.w);
        ((ushort4*)wopb)[i] = o;
        return;
    }
    i -= NO4;
    if (i < NWT) {
        const int k = i / NCOMB, n = i - k * NCOMB;
        float v;
        if (n < 48)      v = xdt[n * DI + k];
        else if (n < 64) v = xb[(n - 48) * DI + k];
        else             v = xc[(n - 64) * DI + k];
        Wt[i] = v;
        return;
    }
    i -= NWT;
    if (i < NA)
        Aneg[i] = -expf(alog[i]);
}

// ---------------------------------------------------------------------------
// Causal depthwise conv (width 4) + bias + SiLU. bf16 in/out, 8 ch/thread.
// ---------------------------------------------------------------------------
__global__ __launch_bounds__(256)
void conv_silu_v8(const u16* __restrict__ xzb, const float* __restrict__ cw,
                  const float* __restrict__ cb, u16* __restrict__ xcvb)
{
    int idx = blockIdx.x * 256 + threadIdx.x;
    if (idx >= L * (DI / 8)) return;
    const int t = idx / (DI / 8);
    const int q = idx - t * (DI / 8);
    const int d = q * 8;

    float w[8][4];
    #pragma unroll
    for (int j = 0; j < 8; ++j)
        *(float4*)w[j] = ((const float4*)cw)[d + j];

    float acc[8];
    {
        const float4 b0 = ((const float4*)cb)[q * 2];
        const float4 b1 = ((const float4*)cb)[q * 2 + 1];
        acc[0] = b0.x; acc[1] = b0.y; acc[2] = b0.z; acc[3] = b0.w;
        acc[4] = b1.x; acc[5] = b1.y; acc[6] = b1.z; acc[7] = b1.w;
    }

    const u16* base = xzb + d;
    #pragma unroll
    for (int j = 0; j < 4; ++j) {
        const int tt = t - 3 + j;
        if (tt >= 0) {
            const u16x8 x8 = *(const u16x8*)(base + (size_t)tt * XZROW);
            #pragma unroll
            for (int k = 0; k < 8; ++k)
                acc[k] = fmaf(w[k][j], bf2f(x8[k]), acc[k]);
        }
    }
    u16x8 o;
    #pragma unroll
    for (int k = 0; k < 8; ++k)
        o[k] = f2bf(silu_f(acc[k]));
    ((u16x8*)xcvb)[idx] = o;
}

// ---------------------------------------------------------------------------
// GEMM2 split-K: part[s][L][80] (bf16) = xcvb[L][K-slice] @ Wt[K-slice][80]
// G2_S=8 splits; each block processes TWO successive 96-wide K-chunks.
// ---------------------------------------------------------------------------
__global__ __launch_bounds__(256)
void gemm2_splitk(const u16* __restrict__ A, const float* __restrict__ Wt,
                  u16* __restrict__ part)
{
    __shared__ float As[G2_KC][65];     // +1 pad
    __shared__ float Ws[G2_KC][80];

    const int tid  = threadIdx.x;
    const int m0   = blockIdx.x * 64;

    const int g  = tid >> 6;
    const int r  = tid & 63;
    const int c0 = g * 20;

    float acc[20];
    #pragma unroll
    for (int j = 0; j < 20; ++j) acc[j] = 0.f;

    #pragma unroll
    for (int half = 0; half < 2; ++half) {
        const int koff = (blockIdx.y * 2 + half) * G2_KC;
        if (half) __syncthreads();          // protect LDS before overwrite

        {
            const int rr = tid >> 2, cg = tid & 3;
            #pragma unroll
            for (int j = 0; j < 6; ++j) {
                const int kk = (j * 4 + cg) * 4;
                const ushort4 v = *(const ushort4*)(A + (size_t)(m0 + rr) * DI + koff + kk);
                As[kk + 0][rr] = bf2f(v.x); As[kk + 1][rr] = bf2f(v.y);
                As[kk + 2][rr] = bf2f(v.z); As[kk + 3][rr] = bf2f(v.w);
            }
        }
        for (int i = tid; i < G2_KC * 80; i += 256)
            (&Ws[0][0])[i] = Wt[(size_t)koff * 80 + i];
        __syncthreads();

        #pragma unroll 2
        for (int k = 0; k < G2_KC; ++k) {
            const float a = As[k][r];
            #pragma unroll
            for (int q = 0; q < 5; ++q) {
                const float4 w = *(const float4*)&Ws[k][c0 + q * 4];
                acc[q * 4 + 0] = fmaf(a, w.x, acc[q * 4 + 0]);
                acc[q * 4 + 1] = fmaf(a, w.y, acc[q * 4 + 1]);
                acc[q * 4 + 2] = fmaf(a, w.z, acc[q * 4 + 2]);
                acc[q * 4 + 3] = fmaf(a, w.w, acc[q * 4 + 3]);
            }
        }
    }

    u16* p = part + (size_t)blockIdx.y * (L * NCOMB)
                  + (size_t)(m0 + r) * NCOMB + c0;
    #pragma unroll
    for (int q = 0; q < 5; ++q) {
        ushort4 o;
        o.x = f2bf(acc[q * 4 + 0]); o.y = f2bf(acc[q * 4 + 1]);
        o.z = f2bf(acc[q * 4 + 2]); o.w = f2bf(acc[q * 4 + 3]);
        *(ushort4*)(p + q * 4) = o;
    }
}

__global__ __launch_bounds__(256)
void gemm2_reduce(const u16* __restrict__ part, float* __restrict__ dtbc)
{
    int i = blockIdx.x * 256 + threadIdx.x;
    if (i >= L * NCOMB) return;
    float s = 0.f;
    #pragma unroll
    for (int j = 0; j < G2_S; ++j)
        s += bf2f(part[(size_t)j * L * NCOMB + i]);
    dtbc[i] = s;
}

// ---------------------------------------------------------------------------
// dt = softplus(dtr @ dtw^T + dtb), stored bf16. Block = 256 ch x 32 t.
// ---------------------------------------------------------------------------
__global__ __launch_bounds__(256)
void dt_k(const float* __restrict__ dtbc, const float* __restrict__ dtw,
          const float* __restrict__ dtb, u16* __restrict__ dt)
{
    __shared__ float dtr_s[32][48];
    const int tid = threadIdx.x;
    const int d   = blockIdx.x * 256 + tid;
    const int t0  = blockIdx.y * 32;

    for (int i = tid; i < 384; i += 256) {
        const int r = i / 12, c = (i - r * 12) * 4;
        const float4 v = *(const float4*)(dtbc + (size_t)(t0 + r) * NCOMB + c);
        *(float4*)&dtr_s[r][c] = v;
    }
    __syncthreads();

    float w[48];
    #pragma unroll
    for (int j = 0; j < 12; ++j) {
        const float4 v = *(const float4*)(dtw + (size_t)d * DR + j * 4);
        w[j * 4 + 0] = v.x; w[j * 4 + 1] = v.y;
        w[j * 4 + 2] = v.z; w[j * 4 + 3] = v.w;
    }
    const float b = dtb[d];

    for (int t = 0; t < 32; ++t) {
        float s = b;
        #pragma unroll
        for (int j = 0; j < 12; ++j) {
            const float4 v = *(const float4*)&dtr_s[t][j * 4];
            s = fmaf(v.x, w[j * 4 + 0], s);
            s = fmaf(v.y, w[j * 4 + 1], s);
            s = fmaf(v.z, w[j * 4 + 2], s);
            s = fmaf(v.w, w[j * 4 + 3], s);
        }
        dt[(size_t)(t0 + t) * DI + d] = f2bf(softplus_f(s));
    }
}

// ---------------------------------------------------------------------------
// Scan pass 1: per-chunk local states (bf16) + dt chunk-sums. CH=32.
// Fast path: Ad[n] = (n+1)*Ad[0] (verified per-thread) -> 1 exp + power tree.
// ---------------------------------------------------------------------------
__global__ __launch_bounds__(256)
void scan1_k(const u16* __restrict__ dt, const u16* __restrict__ xcv,
             const float* __restrict__ dtbc, const float* __restrict__ Aneg,
             u16* __restrict__ hloc, float* __restrict__ Ssum)
{
    __shared__ float Bs[CH][DS];
    const int c = blockIdx.y;
    const int d = blockIdx.x * 256 + threadIdx.x;

    for (int i = threadIdx.x; i < CH * DS; i += 256) {
        int tt = i >> 4, n = i & 15;
        Bs[tt][n] = dtbc[(size_t)(c * CH + tt) * NCOMB + 48 + n];
    }
    __syncthreads();

    float Ad[DS], h[DS];
    #pragma unroll
    for (int q = 0; q < 4; ++q)
        *(float4*)&Ad[q * 4] = *(const float4*)(Aneg + (size_t)d * DS + q * 4);
    #pragma unroll
    for (int n = 0; n < DS; ++n) h[n] = 0.f;

    const float Ad0 = Ad[0];
    bool fastA = true;
    #pragma unroll
    for (int n = 1; n < DS; ++n)
        fastA = fastA && (fabsf(Ad[n] - (float)(n + 1) * Ad0)
                          <= 1e-4f * (float)(n + 1) * fabsf(Ad0));

    size_t base = (size_t)(c * CH) * DI + d;
    float S = 0.f;
    if (fastA) {
        for (int tt = 0; tt < CH; ++tt, base += DI) {
            const float dtv = bf2f(dt[base]);
            const float xv  = bf2f(xcv[base]);
            S += dtv;
            const float xdt = xv * dtv;
            float e[16];
            POWTREE(e, __expf(Ad0 * dtv));
            #pragma unroll
            for (int n = 0; n < DS; ++n)
                h[n] = fmaf(h[n], e[n], xdt * Bs[tt][n]);
        }
    } else {
        for (int tt = 0; tt < CH; ++tt, base += DI) {
            const float dtv = bf2f(dt[base]);
            const float xv  = bf2f(xcv[base]);
            S += dtv;
            const float xdt = xv * dtv;
            #pragma unroll
            for (int n = 0; n < DS; ++n)
                h[n] = fmaf(h[n], __expf(Ad[n] * dtv), xdt * Bs[tt][n]);
        }
    }

    u16* o = hloc + ((size_t)c * DI + d) * DS;
    #pragma unroll
    for (int q = 0; q < 4; ++q) {
        ushort4 pk;
        pk.x = f2bf(h[q * 4 + 0]); pk.y = f2bf(h[q * 4 + 1]);
        pk.z = f2bf(h[q * 4 + 2]); pk.w = f2bf(h[q * 4 + 3]);
        *(ushort4*)(o + q * 4) = pk;
    }
    Ssum[c * DI + d] = S;
}

// ---------------------------------------------------------------------------
// Scan pass 2: scan the NC chunk carries per (d,n); hc bf16 in-place.
// 64-thread blocks x 384: same wave count spread over all 256 CUs.
// ---------------------------------------------------------------------------
__global__ __launch_bounds__(64)
void scan2_k(u16* hc, const float* __restrict__ Ssum,
             const float* __restrict__ Aneg)
{
    const int p = blockIdx.x * 64 + threadIdx.x;
    if (p >= DI * DS) return;
    const int d = p >> 4;
    const float Ad = Aneg[p];
    float h = 0.f;
    for (int c = 0; c < NC; ++c) {
        const size_t o = (size_t)c * DI * DS + p;
        const float hl = bf2f(hc[o]);     // local state
        hc[o] = f2bf(h);                  // overwrite with carry-in
        h = fmaf(h, __expf(Ad * Ssum[c * DI + d]), hl);
    }
}

// ---------------------------------------------------------------------------
// Scan pass 3: replay with carry-in; emit yz bf16 into dead x-half of xzb.
// ---------------------------------------------------------------------------
__global__ __launch_bounds__(256)
void scan3_k(const u16* __restrict__ dt, const u16* __restrict__ xcv,
             const float* __restrict__ dtbc, const float* __restrict__ Aneg,
             const u16* __restrict__ carry, const float* __restrict__ Dp,
             const u16* __restrict__ xzb, u16* __restrict__ ybf)
{
    __shared__ float Bs[CH][DS];
    __shared__ float Cs[CH][DS];
    const int c = blockIdx.y;
    const int d = blockIdx.x * 256 + threadIdx.x;

    for (int i = threadIdx.x; i < CH * DS; i += 256) {
        int tt = i >> 4, n = i & 15;
        Bs[tt][n] = dtbc[(size_t)(c * CH + tt) * NCOMB + 48 + n];
        Cs[tt][n] = dtbc[(size_t)(c * CH + tt) * NCOMB + 64 + n];
    }
    __syncthreads();

    float Ad[DS], h[DS];
    const u16* co = carry + ((size_t)c * DI + d) * DS;
    #pragma unroll
    for (int q = 0; q < 4; ++q) {
        const ushort4 cv = *(const ushort4*)(co + q * 4);
        h[q * 4 + 0] = bf2f(cv.x); h[q * 4 + 1] = bf2f(cv.y);
        h[q * 4 + 2] = bf2f(cv.z); h[q * 4 + 3] = bf2f(cv.w);
    }
    #pragma unroll
    for (int q = 0; q < 4; ++q)
        *(float4*)&Ad[q * 4] = *(const float4*)(Aneg + (size_t)d * DS + q * 4);
    const float Dv = Dp[d];

    const float Ad0 = Ad[0];
    bool fastA = true;
    #pragma unroll
    for (int n = 1; n < DS; ++n)
        fastA = fastA && (fabsf(Ad[n] - (float)(n + 1) * Ad0)
                          <= 1e-4f * (float)(n + 1) * fabsf(Ad0));

    int t = c * CH;
    if (fastA) {
        for (int tt = 0; tt < CH; ++tt, ++t) {
            const size_t o = (size_t)t * DI + d;
            const float dtv = bf2f(dt[o]);
            const float xv  = bf2f(xcv[o]);
            const float xdt = xv * dtv;
            float y = Dv * xv;
            float e[16];
            POWTREE(e, __expf(Ad0 * dtv));
            #pragma unroll
            for (int n = 0; n < DS; ++n) {
                h[n] = fmaf(h[n], e[n], xdt * Bs[tt][n]);
                y = fmaf(h[n], Cs[tt][n], y);
            }
            const float z = bf2f(xzb[(size_t)t * XZROW + DI + d]);
            ybf[(size_t)t * XZROW + d] = f2bf(y * silu_f(z));
        }
    } else {
        for (int tt = 0; tt < CH; ++tt, ++t) {
            const size_t o = (size_t)t * DI + d;
            const float dtv = bf2f(dt[o]);
            const float xv  = bf2f(xcv[o]);
            const float xdt = xv * dtv;
            float y = Dv * xv;
            #pragma unroll
            for (int n = 0; n < DS; ++n) {
                h[n] = fmaf(h[n], __expf(Ad[n] * dtv), xdt * Bs[tt][n]);
                y = fmaf(h[n], Cs[tt][n], y);
            }
            const float z = bf2f(xzb[(size_t)t * XZROW + DI + d]);
            ybf[(size_t)t * XZROW + d] = f2bf(y * silu_f(z));
        }
    }
}

// ---------------------------------------------------------------------------
extern "C" void kernel_launch(void* const* d_in, const int* in_sizes, int n_in,
                              void* d_out, int out_size, void* d_ws, size_t ws_size,
                              hipStream_t stream)
{
    const float* u    = (const float*)d_in[0];
    const float* Wip  = (const float*)d_in[1];
    const float* cw   = (const float*)d_in[2];
    const float* cb   = (const float*)d_in[3];
    const float* xdt  = (const float*)d_in[4];
    const float* xbw  = (const float*)d_in[5];
    const float* xcw  = (const float*)d_in[6];
    const float* dtw  = (const float*)d_in[7];
    const float* dtb  = (const float*)d_in[8];
    const float* alog = (const float*)d_in[9];
    const float* Dp   = (const float*)d_in[10];
    const float* Wop  = (const float*)d_in[11];
    float* out = (float*)d_out;

    // workspace layout (float units) — ~70 MB
    float* ws   = (float*)d_ws;
    u16*   xzb  = (u16*)ws;                          // [4096][3072] bf16
    u16*   xcvb = (u16*)(ws + (size_t)L * XZROW / 2);// [4096][1536] bf16
    float* dtbc = ws + (size_t)L * XZROW / 2
                     + (size_t)L * DI / 2;           // L*NCOMB fp32
    float* dty  = dtbc + (size_t)L * NCOMB;          // L*DI region (g2p, then dt bf16)
    float* Wt   = dty  + (size_t)L * DI;             // DI*NCOMB
    u16*   hc   = (u16*)(Wt + (size_t)DI * NCOMB);   // NC*DI*DS u16
    float* Ssum = Wt + (size_t)DI * NCOMB
                     + (size_t)NC * DI * DS / 2;     // NC*DI
    float* Aneg = Ssum + (size_t)NC * DI;            // DI*DS
    u16*   wopb = (u16*)(Aneg + NA);                 // [768][1536] bf16

    // aliases into regions dead at time of use
    u16*   ubf  = xcvb;                        // [4096][768]  (dead until conv)
    u16*   Wipb = xcvb + (size_t)L * DM;       // [3072][768]  (dead until conv)
    u16*   g2p  = (u16*)dty;                   // [8][4096][80] bf16 (dead after reduce)
    u16*   dtbf = (u16*)dty;                   // [4096][1536] bf16 dt (after reduce)
    u16*   ybf  = xzb;                         // x-half of xzb rows (dead after conv)

    const dim3 blk(256);

    // 1) early packs: ubf, Wipb, wopb (bf16), Wt, Aneg
    pack_early_k<<<(NU4 + NW4 + NO4 + NWT + NA + 255) / 256, blk, 0, stream>>>(
        u, Wip, Wop, xdt, xbw, xcw, alog, ubf, Wipb, wopb, Wt, Aneg);

    // 2) xz = u @ in_proj_w^T   [4096, 3072] bf16 out (bf16 MFMA, XCD swizzle)
    gemm_bf16_bt_o16<<<dim3((2 * DI) / 128, L / 128), blk, 0, stream>>>(
        ubf, Wipb, xzb, L, 2 * DI, DM);

    // 3) causal conv + SiLU -> xcvb (bf16 in/out, 8 ch/thread)
    conv_silu_v8<<<(L * (DI / 8) + 255) / 256, blk, 0, stream>>>(xzb, cw, cb, xcvb);

    // 4) [dt_rank|B|C] = xcvb @ Wt via split-K (8 splits x 2 chunks, bf16 partials)
    gemm2_splitk<<<dim3(L / 64, G2_S), blk, 0, stream>>>(xcvb, Wt, g2p);
    gemm2_reduce<<<(L * NCOMB + 255) / 256, blk, 0, stream>>>(g2p, dtbc);

    // 5) dt = softplus(dtr @ dtw^T + dtb) -> bf16 (overwrites g2p region)
    //    NOTE: dtbf aliases g2p; dt_k reads dtbc (not g2p), so overwrite is safe.
    dt_k<<<dim3(DI / 256, L / 32), blk, 0, stream>>>(dtbc, dtw, dtb, dtbf);

    // 6-8) chunked selective scan (CH=32, 128 chunks)
    scan1_k<<<dim3(DI / 256, NC), blk, 0, stream>>>(
        dtbf, xcvb, dtbc, Aneg, hc, Ssum);
    scan2_k<<<(DI * DS) / 64, dim3(64), 0, stream>>>(hc, Ssum, Aneg);
    scan3_k<<<dim3(DI / 256, NC), blk, 0, stream>>>(
        dtbf, xcvb, dtbc, Aneg, hc, Dp, xzb, ybf);

    // 9) out = yz @ out_proj_w^T   [4096, 768]  (bf16 MFMA, XCD swizzle)
    gemm_bf16_bt_n64<<<dim3(DM / 64, L / 128), blk, 0, stream>>>(
        ybf, XZROW, wopb, DI, out, L, DM, DI);
}